// Round 2
// baseline (4526.057 us; speedup 1.0000x reference)
//
#include <hip/hip_runtime.h>
#include <math.h>

// ---------------- problem constants ----------------
#define PP    25        // h*w spatial positions
#define CCH   640       // channels
#define NCOL  5000      // 200 items * 25 positions
#define NFEA  125       // K_SHOT * h * w
#define SCALE_INV 0.17677669529663687f   // 1/sqrt(32)

// ---------------- workspace float offsets ----------------
#define X_OFF    0L          // [640][5000]
#define XT_OFF   3200000L    // [5000][640]
#define PROJ_OFF 6400000L    // [3][5000][640]  (Q,K,V all stored transposed: [col][o])
#define MMD_OFF  16000000L   // [750]
#define FEAT_OFF 16000768L
#define FEAT_HALF 400000L    // 5*125*640 floats per pair per tensor
#define FEAT_PER_PAIR 800000L

// =====================================================================
// Kernel T: build X[c][col] (for GEMM B-tiles) and XT[col][c] (shortcuts)
// =====================================================================
__global__ __launch_bounds__(256) void t_kernel(const float* __restrict__ sup,
                                                const float* __restrict__ qry,
                                                float* __restrict__ X,
                                                float* __restrict__ XT) {
  __shared__ float lds[16000];
  int item = blockIdx.x;
  const float* src = (item < 50) ? (sup + item * 16000) : (qry + (item - 50) * 16000);
  int tid = threadIdx.x;
  for (int e = tid * 4; e < 16000; e += 1024)
    *(float4*)&lds[e] = *(const float4*)&src[e];
  __syncthreads();
  int ibase = item * PP;
  // X[c][ibase+p] = lds[c*25+p]
  for (int e = tid; e < 16000; e += 256) {
    int c = e / PP, p = e - c * PP;
    X[c * NCOL + ibase + p] = lds[e];
  }
  // XT[(ibase+p)][c]
  for (int e = tid * 4; e < 16000; e += 1024) {
    int p = e / CCH, c = e - p * CCH;
    float4 v;
    v.x = lds[(c + 0) * PP + p];
    v.y = lds[(c + 1) * PP + p];
    v.z = lds[(c + 2) * PP + p];
    v.w = lds[(c + 3) * PP + p];
    *(float4*)&XT[(ibase + p) * CCH + c] = v;
  }
}

// =====================================================================
// Kernel A: projections. out[m][col][o] = sum_c W[m][o][c] * X[c][col]
// (stored TRANSPOSED so downstream frags are contiguous)
// grid (40 col-tiles, 5 o-tiles, 3 matrices), block 256, 8x8 microtile.
// =====================================================================
__global__ __launch_bounds__(256) void proj_kernel(const float* __restrict__ Wq,
                                                   const float* __restrict__ Wk,
                                                   const float* __restrict__ Wv,
                                                   const float* __restrict__ X,
                                                   float* __restrict__ proj) {
  __shared__ float At[128 * 32];  // [o][k]
  __shared__ float Bt[32 * 128];  // [k][col]
  int m = blockIdx.z;
  const float* W = (m == 0) ? Wq : ((m == 1) ? Wk : Wv);
  float* out = proj + (long)m * NCOL * CCH;
  int ctile = blockIdx.x * 128, otile = blockIdx.y * 128;
  int tid = threadIdx.x;
  int tr = tid >> 4, tc = tid & 15;
  float acc[8][8] = {{0.f}};

  for (int kk = 0; kk < 640; kk += 32) {
    // stage A: 128 rows x 32 k  (natural [o][k] orientation of W)
    for (int u = tid; u < 1024; u += 256) {
      int row = u >> 3, seg = u & 7;
      float4 v = *(const float4*)&W[(otile + row) * 640 + kk + seg * 4];
      *(float4*)&At[row * 32 + seg * 4] = v;
    }
    // stage B: 32 k x 128 cols (with tail-tile masking)
    for (int u = tid; u < 1024; u += 256) {
      int k = u >> 5, seg = u & 31;
      int gc = ctile + seg * 4;
      float4 v = make_float4(0.f, 0.f, 0.f, 0.f);
      if (gc < NCOL) v = *(const float4*)&X[(kk + k) * NCOL + gc];
      *(float4*)&Bt[k * 128 + seg * 4] = v;
    }
    __syncthreads();
    for (int kc = 0; kc < 32; kc += 4) {
      float4 a[8];
#pragma unroll
      for (int i = 0; i < 8; i++) a[i] = *(float4*)&At[(tr * 8 + i) * 32 + kc];
#pragma unroll
      for (int d = 0; d < 4; d++) {
        float4 b0 = *(float4*)&Bt[(kc + d) * 128 + tc * 8];
        float4 b1 = *(float4*)&Bt[(kc + d) * 128 + tc * 8 + 4];
#pragma unroll
        for (int i = 0; i < 8; i++) {
          float av = (d == 0) ? a[i].x : (d == 1) ? a[i].y : (d == 2) ? a[i].z : a[i].w;
          acc[i][0] += av * b0.x; acc[i][1] += av * b0.y;
          acc[i][2] += av * b0.z; acc[i][3] += av * b0.w;
          acc[i][4] += av * b1.x; acc[i][5] += av * b1.y;
          acc[i][6] += av * b1.z; acc[i][7] += av * b1.w;
        }
      }
    }
    __syncthreads();
  }
  // transposed store: out[col][o], o contiguous
#pragma unroll
  for (int jc = 0; jc < 8; jc++) {
    int col = ctile + tc * 8 + jc;
    if (col < NCOL) {
      float4 s0 = make_float4(acc[0][jc], acc[1][jc], acc[2][jc], acc[3][jc]);
      float4 s1 = make_float4(acc[4][jc], acc[5][jc], acc[6][jc], acc[7][jc]);
      *(float4*)&out[(long)col * CCH + otile + tr * 8] = s0;
      *(float4*)&out[(long)col * CCH + otile + tr * 8 + 4] = s1;
    }
  }
}

// =====================================================================
// Kernel B: attention + shortcut + feature assembly (uncentered)
// one block per (pair, way); 4 waves x 5 heads each; 5 shots x 2 sides
// =====================================================================
#define WLD 36  // row stride of 28-row frag buffers (qf/kf/vf)

__device__ inline void stage_frag(float* dst, const float* __restrict__ src,
                                  int colbase, int ho, int lane) {
  for (int u = lane; u < 224; u += 64) {   // 28 rows x 8 float4
    int row = u >> 3, seg = u & 7;
    float4 v = make_float4(0.f, 0.f, 0.f, 0.f);
    if (row < 25) v = *(const float4*)&src[(long)(colbase + row) * CCH + ho + seg * 4];
    *(float4*)&dst[row * WLD + seg * 4] = v;
  }
}

__device__ inline void attn_unit(const float* qf, const float* kf, const float* vf,
                                 float* sp, int lane, int r0, int c0,
                                 const float* __restrict__ XTrow,
                                 float* __restrict__ featrow) {
  // ---- scores: S[pq][pk] = sum_hd qf[pq][hd]*kf[pk][hd]
  float s[4][4] = {{0.f}};
#pragma unroll
  for (int hk = 0; hk < 32; hk += 8) {
    float4 qa[4][2], kb[4][2];
#pragma unroll
    for (int i = 0; i < 4; i++) {
      int R = r0 + 8 * i; if (R > 27) R = 27;
      qa[i][0] = *(const float4*)&qf[R * WLD + hk];
      qa[i][1] = *(const float4*)&qf[R * WLD + hk + 4];
      int Cj = c0 + 8 * i; if (Cj > 27) Cj = 27;
      kb[i][0] = *(const float4*)&kf[Cj * WLD + hk];
      kb[i][1] = *(const float4*)&kf[Cj * WLD + hk + 4];
    }
#pragma unroll
    for (int i = 0; i < 4; i++)
#pragma unroll
      for (int j = 0; j < 4; j++) {
        s[i][j] += qa[i][0].x * kb[j][0].x + qa[i][0].y * kb[j][0].y +
                   qa[i][0].z * kb[j][0].z + qa[i][0].w * kb[j][0].w +
                   qa[i][1].x * kb[j][1].x + qa[i][1].y * kb[j][1].y +
                   qa[i][1].z * kb[j][1].z + qa[i][1].w * kb[j][1].w;
      }
  }
#pragma unroll
  for (int i = 0; i < 4; i++)
#pragma unroll
    for (int j = 0; j < 4; j++) {
      int R = r0 + 8 * i, Cj = c0 + 8 * j;
      if (R < 25 && Cj < 28) sp[R * 28 + Cj] = s[i][j];
    }
  __syncthreads();
  // ---- softmax rows (lane r owns row r)
  if (lane < 25) {
    float mx = -1e30f;
    for (int j = 0; j < 25; j++) mx = fmaxf(mx, sp[lane * 28 + j]);
    mx *= SCALE_INV;
    float sum = 0.f;
    for (int j = 0; j < 25; j++) {
      float e = expf(sp[lane * 28 + j] * SCALE_INV - mx);
      sp[lane * 28 + j] = e;
      sum += e;
    }
    float inv = 1.f / sum;
    for (int j = 0; j < 25; j++) sp[lane * 28 + j] *= inv;
  }
  __syncthreads();
  // ---- PV: out[pq][ch] = sum_pk P[pq][pk]*vf[pk][ch]
  float o[4][4] = {{0.f}};
  for (int pk = 0; pk < 25; pk++) {
    float4 vv = *(const float4*)&vf[pk * WLD + c0 * 4];
#pragma unroll
    for (int i = 0; i < 4; i++) {
      int R = r0 + 8 * i; if (R > 24) R = 24;
      float p = sp[R * 28 + pk];
      o[i][0] += p * vv.x; o[i][1] += p * vv.y;
      o[i][2] += p * vv.z; o[i][3] += p * vv.w;
    }
  }
#pragma unroll
  for (int i = 0; i < 4; i++) {
    int R = r0 + 8 * i;
    if (R < 25) {
      float4 sc = *(const float4*)&XTrow[(long)R * CCH + c0 * 4];
      float4 res;
      res.x = o[i][0] + sc.x; res.y = o[i][1] + sc.y;
      res.z = o[i][2] + sc.z; res.w = o[i][3] + sc.w;
      *(float4*)&featrow[(long)R * CCH + c0 * 4] = res;
    }
  }
  __syncthreads();
}

__global__ __launch_bounds__(256) void attn_kernel(const float* __restrict__ proj,
                                                   const float* __restrict__ XT,
                                                   float* __restrict__ sxf,
                                                   float* __restrict__ qxf,
                                                   int chunk_start) {
  __shared__ float lds[4 * 3724];
  int bid = blockIdx.x;
  int lpi = bid / 5, way = bid - lpi * 5;
  int pair = chunk_start + lpi;
  int b = pair / 75;
  int qcol = (50 + pair) * PP;
  int tid = threadIdx.x;
  int w = tid >> 6, lane = tid & 63;
  float* qf = lds + w * 3724;
  float* kf = qf + 1008;
  float* vf = kf + 1008;
  float* sp = vf + 1008;
  int r0 = lane >> 3, c0 = lane & 7;
  const float* Qp = proj;
  const float* Kp = proj + (long)NCOL * CCH;
  const float* Vp = proj + 2L * NCOL * CCH;
  float* featS = sxf + (long)bid * NFEA * CCH;
  float* featQ = qxf + (long)bid * NFEA * CCH;

  for (int hi = 0; hi < 5; hi++) {
    int h = w * 5 + hi;
    int ho = h * 32;
    // side A (sbq): Q from query item, K/V from support; shortcut = support
    stage_frag(qf, Qp, qcol, ho, lane);
    for (int shot = 0; shot < 5; shot++) {
      int scol = (b * 25 + way * 5 + shot) * PP;
      stage_frag(kf, Kp, scol, ho, lane);
      stage_frag(vf, Vp, scol, ho, lane);
      __syncthreads();
      attn_unit(qf, kf, vf, sp, lane, r0, c0,
                XT + (long)scol * CCH + ho,
                featS + (long)shot * 25 * CCH + ho);
    }
    // side B (qbs): Q from support item, K/V from query; shortcut = query
    stage_frag(kf, Kp, qcol, ho, lane);
    stage_frag(vf, Vp, qcol, ho, lane);
    for (int shot = 0; shot < 5; shot++) {
      int scol = (b * 25 + way * 5 + shot) * PP;
      stage_frag(qf, Qp, scol, ho, lane);
      __syncthreads();
      attn_unit(qf, kf, vf, sp, lane, r0, c0,
                XT + (long)qcol * CCH + ho,
                featQ + (long)shot * 25 * CCH + ho);
    }
  }
}

// =====================================================================
// Kernel C: per-(pair,way) MMD from Gram sums with centering folded in
// =====================================================================
#define GLD 36
__global__ __launch_bounds__(256) void gram_kernel(const float* __restrict__ sxf,
                                                   const float* __restrict__ qxf,
                                                   float* __restrict__ mmd,
                                                   int chunk_start) {
  __shared__ float tiles[2 * 128 * GLD];
  __shared__ float meanv[256], nrmv[256];
  __shared__ float2 red2[256];
  __shared__ float resT[3], resD[3];
  int bid = blockIdx.x;
  const float* sbase = sxf + (long)bid * NFEA * CCH;
  const float* qbase = qxf + (long)bid * NFEA * CCH;
  int tid = threadIdx.x;

  // per-row sums / sumsq  (16 lanes per row, coalesced)
  for (int idx = tid; idx < 4000; idx += 256) {
    int r = idx >> 4, seg = idx & 15;
    const float* row = (r < 125) ? (sbase + (long)r * CCH) : (qbase + (long)(r - 125) * CCH);
    float sum = 0.f, ss = 0.f;
#pragma unroll
    for (int jj = 0; jj < 10; jj++) {
      float4 v = *(const float4*)&row[seg * 4 + jj * 64];
      sum += v.x + v.y + v.z + v.w;
      ss += v.x * v.x + v.y * v.y + v.z * v.z + v.w * v.w;
    }
    for (int off = 8; off; off >>= 1) {
      sum += __shfl_xor(sum, off, 16);
      ss  += __shfl_xor(ss,  off, 16);
    }
    if (seg == 0) {
      float mv = sum * (1.0f / 640.0f);
      meanv[r] = mv;
      nrmv[r] = ss - sum * mv;   // ||x||^2 - 640*m^2
    }
  }
  __syncthreads();

  int tr = tid >> 4, tc = tid & 15;
  for (int m = 0; m < 3; m++) {
    const float* Asrc = (m == 1) ? qbase : sbase;
    const float* Bsrc = (m == 0) ? sbase : qbase;
    int aro = (m == 1) ? 125 : 0;
    int bro = (m == 0) ? 0 : 125;
    float* Ta = tiles;
    float* Tb = (m == 2) ? (tiles + 128 * GLD) : tiles;
    float acc[8][8] = {{0.f}};

    for (int kk = 0; kk < 640; kk += 32) {
      for (int u = tid; u < 1024; u += 256) {
        int row = u >> 3, seg = u & 7;
        float4 v = make_float4(0.f, 0.f, 0.f, 0.f);
        if (row < 125) v = *(const float4*)&Asrc[(long)row * CCH + kk + seg * 4];
        *(float4*)&Ta[row * GLD + seg * 4] = v;
      }
      if (m == 2) {
        for (int u = tid; u < 1024; u += 256) {
          int row = u >> 3, seg = u & 7;
          float4 v = make_float4(0.f, 0.f, 0.f, 0.f);
          if (row < 125) v = *(const float4*)&Bsrc[(long)row * CCH + kk + seg * 4];
          *(float4*)&Tb[row * GLD + seg * 4] = v;
        }
      }
      __syncthreads();
      for (int kc = 0; kc < 32; kc += 4) {
        float4 a[8], bb[8];
#pragma unroll
        for (int i = 0; i < 8; i++) a[i] = *(float4*)&Ta[(tr + 16 * i) * GLD + kc];
#pragma unroll
        for (int j = 0; j < 8; j++) bb[j] = *(float4*)&Tb[(tc + 16 * j) * GLD + kc];
#pragma unroll
        for (int i = 0; i < 8; i++)
#pragma unroll
          for (int j = 0; j < 8; j++)
            acc[i][j] += a[i].x * bb[j].x + a[i].y * bb[j].y +
                         a[i].z * bb[j].z + a[i].w * bb[j].w;
      }
      __syncthreads();
    }

    // finalize: d2 -> multi-gaussian kernel -> sums
    float tot = 0.f, dia = 0.f;
#pragma unroll
    for (int i = 0; i < 8; i++) {
      int R = tr + 16 * i;
      if (R < 125) {
        float na = nrmv[aro + R], ma = meanv[aro + R];
#pragma unroll
        for (int j = 0; j < 8; j++) {
          int Cc = tc + 16 * j;
          if (Cc < 125) {
            float d2 = na + nrmv[bro + Cc] - 2.f * acc[i][j] + 1280.f * ma * meanv[bro + Cc];
            d2 = fmaxf(d2, 0.f);
            float e = expf(-0.125f * d2);
            float e2 = e * e, e4 = e2 * e2, e8 = e4 * e4, e16 = e8 * e8;
            float kv = e + e2 + e4 + e8 + e16;
            tot += kv;
            if (m < 2 && R == Cc) dia += kv;
          }
        }
      }
    }
    red2[tid] = make_float2(tot, dia);
    __syncthreads();
    for (int s = 128; s > 0; s >>= 1) {
      if (tid < s) {
        red2[tid].x += red2[tid + s].x;
        red2[tid].y += red2[tid + s].y;
      }
      __syncthreads();
    }
    if (tid == 0) { resT[m] = red2[0].x; resD[m] = red2[0].y; }
    __syncthreads();
  }
  if (tid == 0) {
    float v = (resT[0] - resD[0]) * (1.0f / 15500.0f)
            + (resT[1] - resD[1]) * (1.0f / 15500.0f)
            - resT[2] * (2.0f / 15625.0f);
    mmd[(long)chunk_start * 5 + bid] = v;
  }
}

// =====================================================================
// Kernel D: log-softmax + NLL mean
// =====================================================================
__global__ __launch_bounds__(256) void loss_kernel(const float* __restrict__ mmd,
                                                   const int* __restrict__ qy,
                                                   float* __restrict__ out) {
  __shared__ float red[256];
  int tid = threadIdx.x;
  float val = 0.f;
  if (tid < 150) {
    float l[5];
    float mx = -1e30f;
#pragma unroll
    for (int w = 0; w < 5; w++) {
      l[w] = -mmd[tid * 5 + w] * (1.0f / 12.5f);
      mx = fmaxf(mx, l[w]);
    }
    float sum = 0.f;
#pragma unroll
    for (int w = 0; w < 5; w++) sum += expf(l[w] - mx);
    float lse = mx + logf(sum);
    int y = qy[tid];
    val = -(l[y] - lse);
  }
  red[tid] = val;
  __syncthreads();
  for (int s = 128; s > 0; s >>= 1) {
    if (tid < s) red[tid] += red[tid + s];
    __syncthreads();
  }
  if (tid == 0) out[0] = red[0] * (1.0f / 150.0f);
}

// =====================================================================
extern "C" void kernel_launch(void* const* d_in, const int* in_sizes, int n_in,
                              void* d_out, int out_size, void* d_ws, size_t ws_size,
                              hipStream_t stream) {
  (void)in_sizes; (void)n_in; (void)out_size;
  const float* sup = (const float*)d_in[0];
  const float* qry = (const float*)d_in[2];
  const int* qy = (const int*)d_in[3];
  const float* Wq = (const float*)d_in[4];
  const float* Wk = (const float*)d_in[5];
  const float* Wv = (const float*)d_in[6];
  float* ws = (float*)d_ws;
  float* X = ws + X_OFF;
  float* XT = ws + XT_OFF;
  float* proj = ws + PROJ_OFF;
  float* mmd = ws + MMD_OFF;
  float* feat = ws + FEAT_OFF;
  float* out = (float*)d_out;

  long wsf = (long)(ws_size / 4);
  long avail = wsf - FEAT_OFF;
  long chunkL = avail / FEAT_PER_PAIR;
  int chunk = (chunkL > 150) ? 150 : (chunkL < 1 ? 1 : (int)chunkL);

  hipLaunchKernelGGL(t_kernel, dim3(200), dim3(256), 0, stream, sup, qry, X, XT);
  hipLaunchKernelGGL(proj_kernel, dim3(40, 5, 3), dim3(256), 0, stream, Wq, Wk, Wv, X, proj);
  for (int c0 = 0; c0 < 150; c0 += chunk) {
    int cp = (150 - c0 < chunk) ? (150 - c0) : chunk;
    float* sxf = feat;
    float* qxf = feat + (long)chunk * FEAT_HALF;
    hipLaunchKernelGGL(attn_kernel, dim3(cp * 5), dim3(256), 0, stream, proj, XT, sxf, qxf, c0);
    hipLaunchKernelGGL(gram_kernel, dim3(cp * 5), dim3(256), 0, stream, sxf, qxf, mmd, c0);
  }
  hipLaunchKernelGGL(loss_kernel, dim3(1), dim3(256), 0, stream, mmd, qy, d_out ? out : out);
}

// Round 3
// 2187.301 us; speedup vs baseline: 2.0692x; 2.0692x over previous
//
#include <hip/hip_runtime.h>
#include <math.h>

// ---------------- problem constants ----------------
#define PP    25
#define CCH   640
#define NCOL  5000
#define SCALE_INV 0.17677669529663687f   // 1/sqrt(32)

// ---------------- workspace float offsets ----------------
#define X_OFF    0L          // [640][5000]
#define XT_OFF   3200000L    // [5000][640]
#define PROJ_OFF 6400000L    // [3][5000][640]
#define MMD_OFF  16000000L   // [750]
#define FEAT_OFF 16000768L   // bf16 region: per (pair,way) 256*640 ushorts
#define FEAT_PER_WAY_US 163840L   // 256*640
#define FEAT_PER_PAIR_US 819200L  // 5 ways

typedef __attribute__((ext_vector_type(8)))  short          s16x8;
typedef __attribute__((ext_vector_type(8)))  unsigned short u16x8;
typedef __attribute__((ext_vector_type(4)))  unsigned short u16x4;
typedef __attribute__((ext_vector_type(16))) float          f32x16;

__device__ inline unsigned short f2bf(float x) {
  unsigned u = __float_as_uint(x);
  unsigned r = u + 0x7fff + ((u >> 16) & 1);   // RNE
  return (unsigned short)(r >> 16);
}
__device__ inline float bf2f(unsigned short b) {
  return __uint_as_float(((unsigned)b) << 16);
}

// =====================================================================
// Kernel T: build X[c][col] and XT[col][c]
// =====================================================================
__global__ __launch_bounds__(256) void t_kernel(const float* __restrict__ sup,
                                                const float* __restrict__ qry,
                                                float* __restrict__ X,
                                                float* __restrict__ XT) {
  __shared__ float lds[16000];
  int item = blockIdx.x;
  const float* src = (item < 50) ? (sup + item * 16000) : (qry + (item - 50) * 16000);
  int tid = threadIdx.x;
  for (int e = tid * 4; e < 16000; e += 1024)
    *(float4*)&lds[e] = *(const float4*)&src[e];
  __syncthreads();
  int ibase = item * PP;
  for (int e = tid; e < 16000; e += 256) {
    int c = e / PP, p = e - c * PP;
    X[c * NCOL + ibase + p] = lds[e];
  }
  for (int e = tid * 4; e < 16000; e += 1024) {
    int p = e / CCH, c = e - p * CCH;
    float4 v;
    v.x = lds[(c + 0) * PP + p];
    v.y = lds[(c + 1) * PP + p];
    v.z = lds[(c + 2) * PP + p];
    v.w = lds[(c + 3) * PP + p];
    *(float4*)&XT[(ibase + p) * CCH + c] = v;
  }
}

// =====================================================================
// Kernel A: projections (fp32 VALU GEMM, stores out[col][o])
// =====================================================================
__global__ __launch_bounds__(256) void proj_kernel(const float* __restrict__ Wq,
                                                   const float* __restrict__ Wk,
                                                   const float* __restrict__ Wv,
                                                   const float* __restrict__ X,
                                                   float* __restrict__ proj) {
  __shared__ float At[128 * 32];
  __shared__ float Bt[32 * 128];
  int m = blockIdx.z;
  const float* W = (m == 0) ? Wq : ((m == 1) ? Wk : Wv);
  float* out = proj + (long)m * NCOL * CCH;
  int ctile = blockIdx.x * 128, otile = blockIdx.y * 128;
  int tid = threadIdx.x;
  int tr = tid >> 4, tc = tid & 15;
  float acc[8][8] = {{0.f}};

  for (int kk = 0; kk < 640; kk += 32) {
    for (int u = tid; u < 1024; u += 256) {
      int row = u >> 3, seg = u & 7;
      float4 v = *(const float4*)&W[(otile + row) * 640 + kk + seg * 4];
      *(float4*)&At[row * 32 + seg * 4] = v;
    }
    for (int u = tid; u < 1024; u += 256) {
      int k = u >> 5, seg = u & 31;
      int gc = ctile + seg * 4;
      float4 v = make_float4(0.f, 0.f, 0.f, 0.f);
      if (gc < NCOL) v = *(const float4*)&X[(kk + k) * NCOL + gc];
      *(float4*)&Bt[k * 128 + seg * 4] = v;
    }
    __syncthreads();
    for (int kc = 0; kc < 32; kc += 4) {
      float4 a[8];
#pragma unroll
      for (int i = 0; i < 8; i++) a[i] = *(float4*)&At[(tr * 8 + i) * 32 + kc];
#pragma unroll
      for (int d = 0; d < 4; d++) {
        float4 b0 = *(float4*)&Bt[(kc + d) * 128 + tc * 8];
        float4 b1 = *(float4*)&Bt[(kc + d) * 128 + tc * 8 + 4];
#pragma unroll
        for (int i = 0; i < 8; i++) {
          float av = (d == 0) ? a[i].x : (d == 1) ? a[i].y : (d == 2) ? a[i].z : a[i].w;
          acc[i][0] += av * b0.x; acc[i][1] += av * b0.y;
          acc[i][2] += av * b0.z; acc[i][3] += av * b0.w;
          acc[i][4] += av * b1.x; acc[i][5] += av * b1.y;
          acc[i][6] += av * b1.z; acc[i][7] += av * b1.w;
        }
      }
    }
    __syncthreads();
  }
#pragma unroll
  for (int jc = 0; jc < 8; jc++) {
    int col = ctile + tc * 8 + jc;
    if (col < NCOL) {
      float4 s0 = make_float4(acc[0][jc], acc[1][jc], acc[2][jc], acc[3][jc]);
      float4 s1 = make_float4(acc[4][jc], acc[5][jc], acc[6][jc], acc[7][jc]);
      *(float4*)&out[(long)col * CCH + otile + tr * 8] = s0;
      *(float4*)&out[(long)col * CCH + otile + tr * 8 + 4] = s1;
    }
  }
}

// =====================================================================
// Kernel B: attention; wave-private LDS, NO block barriers.
// Writes bf16 feature rows into combined [256][640] buffer per (pair,way).
// =====================================================================
#define WLD 36

__device__ inline void stage_frag(float* dst, const float* __restrict__ src,
                                  int colbase, int ho, int lane) {
  for (int u = lane; u < 224; u += 64) {
    int row = u >> 3, seg = u & 7;
    float4 v = make_float4(0.f, 0.f, 0.f, 0.f);
    if (row < 25) v = *(const float4*)&src[(long)(colbase + row) * CCH + ho + seg * 4];
    *(float4*)&dst[row * WLD + seg * 4] = v;
  }
}

__device__ inline void attn_unit(const float* qf, const float* kf, const float* vf,
                                 float* sp, int lane, int r0, int c0,
                                 const float* __restrict__ XTrow,
                                 unsigned short* __restrict__ featrow) {
  // scores
  float s[4][4] = {{0.f}};
#pragma unroll
  for (int hk = 0; hk < 32; hk += 8) {
    float4 qa[4][2], kb[4][2];
#pragma unroll
    for (int i = 0; i < 4; i++) {
      int R = r0 + 8 * i; if (R > 27) R = 27;
      qa[i][0] = *(const float4*)&qf[R * WLD + hk];
      qa[i][1] = *(const float4*)&qf[R * WLD + hk + 4];
      int Cj = c0 + 8 * i; if (Cj > 27) Cj = 27;
      kb[i][0] = *(const float4*)&kf[Cj * WLD + hk];
      kb[i][1] = *(const float4*)&kf[Cj * WLD + hk + 4];
    }
#pragma unroll
    for (int i = 0; i < 4; i++)
#pragma unroll
      for (int j = 0; j < 4; j++) {
        s[i][j] += qa[i][0].x * kb[j][0].x + qa[i][0].y * kb[j][0].y +
                   qa[i][0].z * kb[j][0].z + qa[i][0].w * kb[j][0].w +
                   qa[i][1].x * kb[j][1].x + qa[i][1].y * kb[j][1].y +
                   qa[i][1].z * kb[j][1].z + qa[i][1].w * kb[j][1].w;
      }
  }
#pragma unroll
  for (int i = 0; i < 4; i++)
#pragma unroll
    for (int j = 0; j < 4; j++) {
      int R = r0 + 8 * i, Cj = c0 + 8 * j;
      if (R < 25 && Cj < 28) sp[R * 28 + Cj] = s[i][j];
    }
  // softmax rows — intra-wave LDS ordering, no barrier needed
  if (lane < 25) {
    float mx = -1e30f;
    for (int j = 0; j < 25; j++) mx = fmaxf(mx, sp[lane * 28 + j]);
    mx *= SCALE_INV;
    float sum = 0.f;
    for (int j = 0; j < 25; j++) {
      float e = __expf(sp[lane * 28 + j] * SCALE_INV - mx);
      sp[lane * 28 + j] = e;
      sum += e;
    }
    float inv = 1.f / sum;
    for (int j = 0; j < 25; j++) sp[lane * 28 + j] *= inv;
  }
  // PV
  float o[4][4] = {{0.f}};
  for (int pk = 0; pk < 25; pk++) {
    float4 vv = *(const float4*)&vf[pk * WLD + c0 * 4];
#pragma unroll
    for (int i = 0; i < 4; i++) {
      int R = r0 + 8 * i; if (R > 24) R = 24;
      float p = sp[R * 28 + pk];
      o[i][0] += p * vv.x; o[i][1] += p * vv.y;
      o[i][2] += p * vv.z; o[i][3] += p * vv.w;
    }
  }
#pragma unroll
  for (int i = 0; i < 4; i++) {
    int R = r0 + 8 * i;
    if (R < 25) {
      float4 sc = *(const float4*)&XTrow[(long)R * CCH + c0 * 4];
      u16x4 r;
      r.x = f2bf(o[i][0] + sc.x);
      r.y = f2bf(o[i][1] + sc.y);
      r.z = f2bf(o[i][2] + sc.z);
      r.w = f2bf(o[i][3] + sc.w);
      *(u16x4*)&featrow[R * CCH + c0 * 4] = r;
    }
  }
}

__global__ __launch_bounds__(256) void attn_kernel(const float* __restrict__ proj,
                                                   const float* __restrict__ XT,
                                                   unsigned short* __restrict__ feat,
                                                   int chunk_start) {
  __shared__ float lds[4 * 3724];
  int bid = blockIdx.x;
  int lpi = bid / 5, way = bid - lpi * 5;
  int pair = chunk_start + lpi;
  int b = pair / 75;
  int qcol = (50 + pair) * PP;
  int tid = threadIdx.x;
  int w = tid >> 6, lane = tid & 63;
  float* qf = lds + w * 3724;
  float* kf = qf + 1008;
  float* vf = kf + 1008;
  float* sp = vf + 1008;
  int r0 = lane >> 3, c0 = lane & 7;
  const float* Qp = proj;
  const float* Kp = proj + (long)NCOL * CCH;
  const float* Vp = proj + 2L * NCOL * CCH;
  unsigned short* fb = feat + (long)bid * FEAT_PER_WAY_US;

  for (int hi = 0; hi < 5; hi++) {
    int h = w * 5 + hi;
    int ho = h * 32;
    // side A (sbq): rows 0..124
    stage_frag(qf, Qp, qcol, ho, lane);
    for (int shot = 0; shot < 5; shot++) {
      int scol = (b * 25 + way * 5 + shot) * PP;
      stage_frag(kf, Kp, scol, ho, lane);
      stage_frag(vf, Vp, scol, ho, lane);
      attn_unit(qf, kf, vf, sp, lane, r0, c0,
                XT + (long)scol * CCH + ho,
                fb + (long)(shot * 25) * CCH + ho);
    }
    // side B (qbs): rows 125..249
    stage_frag(kf, Kp, qcol, ho, lane);
    stage_frag(vf, Vp, qcol, ho, lane);
    for (int shot = 0; shot < 5; shot++) {
      int scol = (b * 25 + way * 5 + shot) * PP;
      stage_frag(qf, Qp, scol, ho, lane);
      attn_unit(qf, kf, vf, sp, lane, r0, c0,
                XT + (long)qcol * CCH + ho,
                fb + (long)(125 + shot * 25) * CCH + ho);
    }
  }
}

// =====================================================================
// Kernel C: MFMA bf16 combined 250x250 Gram -> multi-gaussian sums -> mmd
// one block (512 thr, 8 waves) per (pair,way). Tile grid 8x8 of 32x32;
// wave w=(wr,wc) owns ti in {wr+2a}, tj in {wc+4b}.
// LDS: single [256][64] bf16 K-chunk, XOR-16B-granule swizzled.
// =====================================================================
__global__ __launch_bounds__(512) void gram_kernel(const unsigned short* __restrict__ feat,
                                                   float* __restrict__ mmd,
                                                   int chunk_start) {
  __shared__ __align__(16) unsigned short tile[16384];  // 256 rows x 64 bf16 (swizzled)
  __shared__ float meanv[256], nrmv[256];
  __shared__ float red[24];
  int bid = blockIdx.x;
  const unsigned short* fb = feat + (long)bid * FEAT_PER_WAY_US;
  int tid = threadIdx.x;

  // ---- per-row stats (2 threads/row) ----
  {
    int r = tid >> 1, half = tid & 1;
    const unsigned short* p = fb + r * CCH + half * 320;
    float sum = 0.f, ss = 0.f;
    for (int j = 0; j < 320; j += 8) {
      u16x8 v = *(const u16x8*)&p[j];
#pragma unroll
      for (int e = 0; e < 8; e++) { float f = bf2f(v[e]); sum += f; ss += f * f; }
    }
    sum += __shfl_xor(sum, 1);
    ss  += __shfl_xor(ss, 1);
    if (half == 0) {
      meanv[r] = sum * (1.f / 640.f);
      nrmv[r]  = ss - sum * sum * (1.f / 640.f);
    }
  }

  int w = tid >> 6, lane = tid & 63;
  int wr = w >> 2, wc = w & 3;
  int lr = lane & 31, ksel = lane >> 5;

  f32x16 acc[4][2];
#pragma unroll
  for (int a = 0; a < 4; a++)
#pragma unroll
    for (int b = 0; b < 2; b++)
#pragma unroll
      for (int e = 0; e < 16; e++) acc[a][b][e] = 0.f;

  // staging: thread t loads 64B (4 granules) of row t>>1
  int sr = tid >> 1, sg0 = (tid & 1) * 4;
  const unsigned short* gsrc = fb + sr * CCH + sg0 * 8;

  u16x8 pf[4];
#pragma unroll
  for (int gi = 0; gi < 4; gi++) pf[gi] = *(const u16x8*)&gsrc[gi * 8];

  for (int kc = 0; kc < 10; kc++) {
    __syncthreads();   // prev compute done -> safe to overwrite tile
#pragma unroll
    for (int gi = 0; gi < 4; gi++) {
      int g = sg0 + gi;
      *(u16x8*)&tile[sr * 64 + ((g ^ (sr & 7)) << 3)] = pf[gi];
    }
    if (kc < 9) {
      const unsigned short* ns = gsrc + (kc + 1) * 64;
#pragma unroll
      for (int gi = 0; gi < 4; gi++) pf[gi] = *(const u16x8*)&ns[gi * 8];
    }
    __syncthreads();   // tile ready
#pragma unroll
    for (int ks = 0; ks < 4; ks++) {
      int gk = ks * 2 + ksel;
      s16x8 af[4], bfv[2];
#pragma unroll
      for (int a = 0; a < 4; a++) {
        int R = (wr + 2 * a) * 32 + lr;
        af[a] = *(const s16x8*)&tile[R * 64 + ((gk ^ (R & 7)) << 3)];
      }
#pragma unroll
      for (int b = 0; b < 2; b++) {
        int R = (wc + 4 * b) * 32 + lr;
        bfv[b] = *(const s16x8*)&tile[R * 64 + ((gk ^ (R & 7)) << 3)];
      }
#pragma unroll
      for (int a = 0; a < 4; a++)
#pragma unroll
        for (int b = 0; b < 2; b++)
          acc[a][b] = __builtin_amdgcn_mfma_f32_32x32x16_bf16(af[a], bfv[b], acc[a][b], 0, 0, 0);
    }
  }

  // ---- epilogue: d2 -> 5-term gaussian kernel -> region sums ----
  float s_ss = 0.f, s_qq = 0.f, s_x = 0.f;
#pragma unroll
  for (int a = 0; a < 4; a++) {
    int ti = wr + 2 * a;
#pragma unroll
    for (int b = 0; b < 2; b++) {
      int tj = wc + 4 * b;
      int col = tj * 32 + lr;
#pragma unroll
      for (int rg = 0; rg < 16; rg++) {
        int row = ti * 32 + (rg & 3) + 8 * (rg >> 2) + 4 * ksel;
        if (row < 250 && col < 250) {
          float d2 = nrmv[row] + nrmv[col] - 2.f * acc[a][b][rg]
                   + 1280.f * meanv[row] * meanv[col];
          d2 = fmaxf(d2, 0.f);
          float e = __expf(-0.125f * d2);
          float e2 = e * e, e4 = e2 * e2, e8 = e4 * e4, e16 = e8 * e8;
          float kv = e + e2 + e4 + e8 + e16;
          bool rs = row < 125, cs = col < 125;
          if (rs && cs)        { if (row != col) s_ss += kv; }
          else if (!rs && !cs) { if (row != col) s_qq += kv; }
          else                 s_x += kv;   // counts Kqs + Ksq = 2*tot(Kqs)
        }
      }
    }
  }
#pragma unroll
  for (int off = 32; off; off >>= 1) {
    s_ss += __shfl_xor(s_ss, off);
    s_qq += __shfl_xor(s_qq, off);
    s_x  += __shfl_xor(s_x, off);
  }
  if (lane == 0) { red[w * 3] = s_ss; red[w * 3 + 1] = s_qq; red[w * 3 + 2] = s_x; }
  __syncthreads();
  if (tid == 0) {
    float a = 0.f, b = 0.f, c = 0.f;
    for (int i = 0; i < 8; i++) { a += red[i * 3]; b += red[i * 3 + 1]; c += red[i * 3 + 2]; }
    // mmd = (ss)/N(N-1) + (qq)/N(N-1) - 2/N^2 * (x/2)
    mmd[(long)chunk_start * 5 + bid] = a * (1.f / 15500.f) + b * (1.f / 15500.f) - c * (1.f / 15625.f);
  }
}

// =====================================================================
// Kernel D: log-softmax + NLL mean
// =====================================================================
__global__ __launch_bounds__(256) void loss_kernel(const float* __restrict__ mmd,
                                                   const int* __restrict__ qy,
                                                   float* __restrict__ out) {
  __shared__ float red[256];
  int tid = threadIdx.x;
  float val = 0.f;
  if (tid < 150) {
    float l[5];
    float mx = -1e30f;
#pragma unroll
    for (int w = 0; w < 5; w++) {
      l[w] = -mmd[tid * 5 + w] * (1.0f / 12.5f);
      mx = fmaxf(mx, l[w]);
    }
    float sum = 0.f;
#pragma unroll
    for (int w = 0; w < 5; w++) sum += __expf(l[w] - mx);
    float lse = mx + logf(sum);
    int y = qy[tid];
    val = -(l[y] - lse);
  }
  red[tid] = val;
  __syncthreads();
  for (int s = 128; s > 0; s >>= 1) {
    if (tid < s) red[tid] += red[tid + s];
    __syncthreads();
  }
  if (tid == 0) out[0] = red[0] * (1.0f / 150.0f);
}

// =====================================================================
extern "C" void kernel_launch(void* const* d_in, const int* in_sizes, int n_in,
                              void* d_out, int out_size, void* d_ws, size_t ws_size,
                              hipStream_t stream) {
  (void)in_sizes; (void)n_in; (void)out_size;
  const float* sup = (const float*)d_in[0];
  const float* qry = (const float*)d_in[2];
  const int* qy = (const int*)d_in[3];
  const float* Wq = (const float*)d_in[4];
  const float* Wk = (const float*)d_in[5];
  const float* Wv = (const float*)d_in[6];
  float* ws = (float*)d_ws;
  float* X = ws + X_OFF;
  float* XT = ws + XT_OFF;
  float* proj = ws + PROJ_OFF;
  float* mmd = ws + MMD_OFF;
  unsigned short* feat = (unsigned short*)(ws + FEAT_OFF);
  float* out = (float*)d_out;

  long wsf = (long)(ws_size / 4);
  long avail_us = (wsf - FEAT_OFF) * 2;   // ushorts available for features
  long chunkL = avail_us / FEAT_PER_PAIR_US;
  int chunk = (chunkL > 150) ? 150 : (chunkL < 1 ? 1 : (int)chunkL);

  hipLaunchKernelGGL(t_kernel, dim3(200), dim3(256), 0, stream, sup, qry, X, XT);
  hipLaunchKernelGGL(proj_kernel, dim3(40, 5, 3), dim3(256), 0, stream, Wq, Wk, Wv, X, proj);
  for (int c0 = 0; c0 < 150; c0 += chunk) {
    int cp = (150 - c0 < chunk) ? (150 - c0) : chunk;
    hipLaunchKernelGGL(attn_kernel, dim3(cp * 5), dim3(256), 0, stream, proj, XT, feat, c0);
    hipLaunchKernelGGL(gram_kernel, dim3(cp * 5), dim3(512), 0, stream, feat, mmd, c0);
  }
  hipLaunchKernelGGL(loss_kernel, dim3(1), dim3(256), 0, stream, mmd, qy, out);
}

// Round 4
// 1934.767 us; speedup vs baseline: 2.3393x; 1.1305x over previous
//
#include <hip/hip_runtime.h>
#include <math.h>

// ---------------- problem constants ----------------
#define PP    25
#define CCH   640
#define NCOL  5000
#define SCALE_INV 0.17677669529663687f   // 1/sqrt(32)

// ---------------- workspace float offsets ----------------
#define X_OFF    0L          // [640][5000]
#define XT_OFF   3200000L    // [5000][640]
#define PROJ_OFF 6400000L    // [3][5000][640]
#define MMD_OFF  16000000L   // [750]
#define FEAT_OFF 16000768L   // bf16 region, head-blocked [way][20][250][32]
#define FEAT_PER_WAY_US 160000L   // 20*250*32
#define FEAT_PER_PAIR_US 800000L  // 5 ways

typedef __attribute__((ext_vector_type(8)))  short          s16x8;
typedef __attribute__((ext_vector_type(8)))  unsigned short u16x8;
typedef __attribute__((ext_vector_type(4)))  unsigned short u16x4;
typedef __attribute__((ext_vector_type(16))) float          f32x16;

__device__ inline unsigned short f2bf(float x) {
  unsigned u = __float_as_uint(x);
  unsigned r = u + 0x7fff + ((u >> 16) & 1);   // RNE
  return (unsigned short)(r >> 16);
}

// =====================================================================
// Kernel T: build X[c][col] and XT[col][c]
// =====================================================================
__global__ __launch_bounds__(256) void t_kernel(const float* __restrict__ sup,
                                                const float* __restrict__ qry,
                                                float* __restrict__ X,
                                                float* __restrict__ XT) {
  __shared__ float lds[16000];
  int item = blockIdx.x;
  const float* src = (item < 50) ? (sup + item * 16000) : (qry + (item - 50) * 16000);
  int tid = threadIdx.x;
  for (int e = tid * 4; e < 16000; e += 1024)
    *(float4*)&lds[e] = *(const float4*)&src[e];
  __syncthreads();
  int ibase = item * PP;
  for (int e = tid; e < 16000; e += 256) {
    int c = e / PP, p = e - c * PP;
    X[c * NCOL + ibase + p] = lds[e];
  }
  for (int e = tid * 4; e < 16000; e += 1024) {
    int p = e / CCH, c = e - p * CCH;
    float4 v;
    v.x = lds[(c + 0) * PP + p];
    v.y = lds[(c + 1) * PP + p];
    v.z = lds[(c + 2) * PP + p];
    v.w = lds[(c + 3) * PP + p];
    *(float4*)&XT[(ibase + p) * CCH + c] = v;
  }
}

// =====================================================================
// Kernel A: projections (fp32 VALU GEMM, stores out[col][o])
// =====================================================================
__global__ __launch_bounds__(256) void proj_kernel(const float* __restrict__ Wq,
                                                   const float* __restrict__ Wk,
                                                   const float* __restrict__ Wv,
                                                   const float* __restrict__ X,
                                                   float* __restrict__ proj) {
  __shared__ float At[128 * 32];
  __shared__ float Bt[32 * 128];
  int m = blockIdx.z;
  const float* W = (m == 0) ? Wq : ((m == 1) ? Wk : Wv);
  float* out = proj + (long)m * NCOL * CCH;
  int ctile = blockIdx.x * 128, otile = blockIdx.y * 128;
  int tid = threadIdx.x;
  int tr = tid >> 4, tc = tid & 15;
  float acc[8][8] = {{0.f}};

  for (int kk = 0; kk < 640; kk += 32) {
    for (int u = tid; u < 1024; u += 256) {
      int row = u >> 3, seg = u & 7;
      float4 v = *(const float4*)&W[(otile + row) * 640 + kk + seg * 4];
      *(float4*)&At[row * 32 + seg * 4] = v;
    }
    for (int u = tid; u < 1024; u += 256) {
      int k = u >> 5, seg = u & 31;
      int gc = ctile + seg * 4;
      float4 v = make_float4(0.f, 0.f, 0.f, 0.f);
      if (gc < NCOL) v = *(const float4*)&X[(kk + k) * NCOL + gc];
      *(float4*)&Bt[k * 128 + seg * 4] = v;
    }
    __syncthreads();
    for (int kc = 0; kc < 32; kc += 4) {
      float4 a[8];
#pragma unroll
      for (int i = 0; i < 8; i++) a[i] = *(float4*)&At[(tr * 8 + i) * 32 + kc];
#pragma unroll
      for (int d = 0; d < 4; d++) {
        float4 b0 = *(float4*)&Bt[(kc + d) * 128 + tc * 8];
        float4 b1 = *(float4*)&Bt[(kc + d) * 128 + tc * 8 + 4];
#pragma unroll
        for (int i = 0; i < 8; i++) {
          float av = (d == 0) ? a[i].x : (d == 1) ? a[i].y : (d == 2) ? a[i].z : a[i].w;
          acc[i][0] += av * b0.x; acc[i][1] += av * b0.y;
          acc[i][2] += av * b0.z; acc[i][3] += av * b0.w;
          acc[i][4] += av * b1.x; acc[i][5] += av * b1.y;
          acc[i][6] += av * b1.z; acc[i][7] += av * b1.w;
        }
      }
    }
    __syncthreads();
  }
#pragma unroll
  for (int jc = 0; jc < 8; jc++) {
    int col = ctile + tc * 8 + jc;
    if (col < NCOL) {
      float4 s0 = make_float4(acc[0][jc], acc[1][jc], acc[2][jc], acc[3][jc]);
      float4 s1 = make_float4(acc[4][jc], acc[5][jc], acc[6][jc], acc[7][jc]);
      *(float4*)&out[(long)col * CCH + otile + tr * 8] = s0;
      *(float4*)&out[(long)col * CCH + otile + tr * 8 + 4] = s1;
    }
  }
}

// =====================================================================
// Kernel B: attention. Wave-private LDS q/k/v frags; register softmax
// (shfl_xor reduce over the 8 c0-lanes); PV gathers P via bpermute.
// Writes bf16 features head-blocked: fb[h][row][32ch] -> 512B/instr stores.
// =====================================================================
#define WLD 36

__device__ inline void stage_frag(float* dst, const float* __restrict__ src,
                                  int colbase, int ho, int lane) {
  for (int u = lane; u < 224; u += 64) {
    int row = u >> 3, seg = u & 7;
    float4 v = make_float4(0.f, 0.f, 0.f, 0.f);
    if (row < 25) v = *(const float4*)&src[(long)(colbase + row) * CCH + ho + seg * 4];
    *(float4*)&dst[row * WLD + seg * 4] = v;
  }
}

__device__ inline void stage_load(float4* reg, const float* __restrict__ src,
                                  int colbase, int ho, int lane) {
  int q = 0;
  for (int u = lane; u < 224; u += 64, ++q) {
    int row = u >> 3, seg = u & 7;
    float4 v = make_float4(0.f, 0.f, 0.f, 0.f);
    if (row < 25) v = *(const float4*)&src[(long)(colbase + row) * CCH + ho + seg * 4];
    reg[q] = v;
  }
}

__device__ inline void stage_write(float* dst, const float4* reg, int lane) {
  int q = 0;
  for (int u = lane; u < 224; u += 64, ++q) {
    int row = u >> 3, seg = u & 7;
    *(float4*)&dst[row * WLD + seg * 4] = reg[q];
  }
}

__device__ inline void attn_unit(const float* qf, const float* kf, const float* vf,
                                 int lane, int r0, int c0,
                                 const float* __restrict__ XTrow,
                                 unsigned short* __restrict__ featrow) {
  // ---- scores s[i][j] = S[r0+8i][c0+8j]
  float s[4][4] = {{0.f}};
#pragma unroll
  for (int hk = 0; hk < 32; hk += 8) {
    float4 qa[4][2], kb[4][2];
#pragma unroll
    for (int i = 0; i < 4; i++) {
      int R = r0 + 8 * i; if (R > 27) R = 27;
      qa[i][0] = *(const float4*)&qf[R * WLD + hk];
      qa[i][1] = *(const float4*)&qf[R * WLD + hk + 4];
      int Cj = c0 + 8 * i; if (Cj > 27) Cj = 27;
      kb[i][0] = *(const float4*)&kf[Cj * WLD + hk];
      kb[i][1] = *(const float4*)&kf[Cj * WLD + hk + 4];
    }
#pragma unroll
    for (int i = 0; i < 4; i++)
#pragma unroll
      for (int j = 0; j < 4; j++) {
        s[i][j] += qa[i][0].x * kb[j][0].x + qa[i][0].y * kb[j][0].y +
                   qa[i][0].z * kb[j][0].z + qa[i][0].w * kb[j][0].w +
                   qa[i][1].x * kb[j][1].x + qa[i][1].y * kb[j][1].y +
                   qa[i][1].z * kb[j][1].z + qa[i][1].w * kb[j][1].w;
      }
  }
  // ---- register softmax: row R lives across the 8 lanes sharing r0
  float p[4][4];
  float sminv[4];
#pragma unroll
  for (int i = 0; i < 4; i++) {
    float mx = -1e30f;
#pragma unroll
    for (int j = 0; j < 4; j++)
      if (c0 + 8 * j < 25) mx = fmaxf(mx, s[i][j]);
    mx = fmaxf(mx, __shfl_xor(mx, 1));
    mx = fmaxf(mx, __shfl_xor(mx, 2));
    mx = fmaxf(mx, __shfl_xor(mx, 4));
    float sum = 0.f;
#pragma unroll
    for (int j = 0; j < 4; j++) {
      float e = 0.f;
      if (c0 + 8 * j < 25) e = __expf((s[i][j] - mx) * SCALE_INV);
      p[i][j] = e;
      sum += e;
    }
    sum += __shfl_xor(sum, 1);
    sum += __shfl_xor(sum, 2);
    sum += __shfl_xor(sum, 4);
    sminv[i] = 1.f / sum;
  }
  // ---- PV: gather P via bpermute (src lane = same r0-group, c0 = pk&7)
  float o[4][4] = {{0.f}};
  int srcbase = lane & 56;
#pragma unroll
  for (int jj = 0; jj < 4; jj++)
#pragma unroll
    for (int pk2 = 0; pk2 < 8; pk2++) {
      int pk = jj * 8 + pk2;
      if (pk < 25) {
        float4 vv = *(const float4*)&vf[pk * WLD + c0 * 4];
        int src = srcbase | pk2;
#pragma unroll
        for (int i = 0; i < 4; i++) {
          float pi = __shfl(p[i][jj], src);
          o[i][0] += pi * vv.x; o[i][1] += pi * vv.y;
          o[i][2] += pi * vv.z; o[i][3] += pi * vv.w;
        }
      }
    }
  // ---- normalize + shortcut + bf16 store (head-blocked, contiguous)
#pragma unroll
  for (int i = 0; i < 4; i++) {
    int R = r0 + 8 * i;
    if (R < 25) {
      float4 sc = *(const float4*)&XTrow[(long)R * CCH + c0 * 4];
      u16x4 rr;
      rr.x = f2bf(o[i][0] * sminv[i] + sc.x);
      rr.y = f2bf(o[i][1] * sminv[i] + sc.y);
      rr.z = f2bf(o[i][2] * sminv[i] + sc.z);
      rr.w = f2bf(o[i][3] * sminv[i] + sc.w);
      *(u16x4*)&featrow[R * 32 + c0 * 4] = rr;
    }
  }
}

__global__ __launch_bounds__(256) void attn_kernel(const float* __restrict__ proj,
                                                   const float* __restrict__ XT,
                                                   unsigned short* __restrict__ feat,
                                                   int chunk_start) {
  __shared__ float lds[4 * 3024];
  int bid = blockIdx.x;
  int lpi = bid / 5, way = bid - lpi * 5;
  int pair = chunk_start + lpi;
  int b = pair / 75;
  int qcol = (50 + pair) * PP;
  int tid = threadIdx.x;
  int w = tid >> 6, lane = tid & 63;
  float* qf = lds + w * 3024;
  float* kf = qf + 1008;
  float* vf = kf + 1008;
  int r0 = lane >> 3, c0 = lane & 7;
  const float* Qp = proj;
  const float* Kp = proj + (long)NCOL * CCH;
  const float* Vp = proj + 2L * NCOL * CCH;
  unsigned short* fb = feat + (long)bid * FEAT_PER_WAY_US;

  float4 pk_[4], pv_[4], pq_[4];

  for (int hi = 0; hi < 5; hi++) {
    int h = w * 5 + hi;
    int ho = h * 32;
    int sbase = (b * 25 + way * 5) * PP;
    // ---- side A (sbq): rows 0..124
    stage_frag(qf, Qp, qcol, ho, lane);
    stage_frag(kf, Kp, sbase, ho, lane);
    stage_frag(vf, Vp, sbase, ho, lane);
    for (int shot = 0; shot < 5; shot++) {
      if (shot < 4) {
        stage_load(pk_, Kp, sbase + (shot + 1) * PP, ho, lane);
        stage_load(pv_, Vp, sbase + (shot + 1) * PP, ho, lane);
      }
      attn_unit(qf, kf, vf, lane, r0, c0,
                XT + (long)(sbase + shot * PP) * CCH + ho,
                fb + (long)(h * 250 + shot * 25) * 32);
      if (shot < 4) { stage_write(kf, pk_, lane); stage_write(vf, pv_, lane); }
    }
    // ---- side B (qbs): rows 125..249
    stage_frag(kf, Kp, qcol, ho, lane);
    stage_frag(vf, Vp, qcol, ho, lane);
    stage_frag(qf, Qp, sbase, ho, lane);
    for (int shot = 0; shot < 5; shot++) {
      if (shot < 4) stage_load(pq_, Qp, sbase + (shot + 1) * PP, ho, lane);
      attn_unit(qf, kf, vf, lane, r0, c0,
                XT + (long)qcol * CCH + ho,
                fb + (long)(h * 250 + 125 + shot * 25) * 32);
      if (shot < 4) stage_write(qf, pq_, lane);
    }
  }
}

// =====================================================================
// Kernel C: MFMA bf16 Gram (256x256, rows 0..249 = features, row 250 = ones)
// mean/norm harvested from Gram col 250 and diagonal. Head-blocked input.
// =====================================================================
__device__ inline void gram_load(u16x8* pf, const unsigned short* __restrict__ fb,
                                 int sr, int half, int kc) {
#pragma unroll
  for (int gi = 0; gi < 4; gi++) {
    u16x8 v;
    if (sr < 250) {
      v = *(const u16x8*)&fb[(long)((2 * kc + half) * 250 + sr) * 32 + gi * 8];
    } else if (sr == 250) {
#pragma unroll
      for (int e = 0; e < 8; e++) v[e] = 0x3F80;   // bf16 1.0
    } else {
#pragma unroll
      for (int e = 0; e < 8; e++) v[e] = 0;
    }
    pf[gi] = v;
  }
}

__global__ __launch_bounds__(512) void gram_kernel(const unsigned short* __restrict__ feat,
                                                   float* __restrict__ mmd,
                                                   int chunk_start) {
  __shared__ __align__(16) unsigned short tile[16384];  // 256 x 64 bf16, swizzled
  __shared__ float sums[256], nrmsq[256], meanv[256], nrmv[256];
  __shared__ float red[24];
  int bid = blockIdx.x;
  const unsigned short* fb = feat + (long)bid * FEAT_PER_WAY_US;
  int tid = threadIdx.x;
  int w = tid >> 6, lane = tid & 63;
  int wr = w >> 2, wc = w & 3;
  int lr = lane & 31, ksel = lane >> 5;
  int sr = tid >> 1, half = tid & 1;

  f32x16 acc[4][2];
#pragma unroll
  for (int a = 0; a < 4; a++)
#pragma unroll
    for (int b2 = 0; b2 < 2; b2++)
#pragma unroll
      for (int e = 0; e < 16; e++) acc[a][b2][e] = 0.f;

  u16x8 pf[4];
  gram_load(pf, fb, sr, half, 0);

  for (int kc = 0; kc < 10; kc++) {
    __syncthreads();
#pragma unroll
    for (int gi = 0; gi < 4; gi++) {
      int g = half * 4 + gi;
      *(u16x8*)&tile[sr * 64 + ((g ^ (sr & 7)) << 3)] = pf[gi];
    }
    if (kc < 9) gram_load(pf, fb, sr, half, kc + 1);
    __syncthreads();
#pragma unroll
    for (int ks = 0; ks < 4; ks++) {
      int gk = ks * 2 + ksel;
      s16x8 af[4], bfv[2];
#pragma unroll
      for (int a = 0; a < 4; a++) {
        int R = (wr + 2 * a) * 32 + lr;
        af[a] = *(const s16x8*)&tile[R * 64 + ((gk ^ (R & 7)) << 3)];
      }
#pragma unroll
      for (int b2 = 0; b2 < 2; b2++) {
        int R = (wc + 4 * b2) * 32 + lr;
        bfv[b2] = *(const s16x8*)&tile[R * 64 + ((gk ^ (R & 7)) << 3)];
      }
#pragma unroll
      for (int a = 0; a < 4; a++)
#pragma unroll
        for (int b2 = 0; b2 < 2; b2++)
          acc[a][b2] = __builtin_amdgcn_mfma_f32_32x32x16_bf16(af[a], bfv[b2], acc[a][b2], 0, 0, 0);
    }
  }

  // ---- harvest row sums (col 250) and squared norms (diagonal)
#pragma unroll
  for (int a = 0; a < 4; a++) {
    int ti = wr + 2 * a;
#pragma unroll
    for (int b2 = 0; b2 < 2; b2++) {
      int tj = wc + 4 * b2;
      int col = tj * 32 + lr;
      if (col == 250) {
#pragma unroll
        for (int rg = 0; rg < 16; rg++) {
          int row = ti * 32 + (rg & 3) + 8 * (rg >> 2) + 4 * ksel;
          if (row < 250) sums[row] = acc[a][b2][rg];
        }
      }
      if (ti == tj) {
#pragma unroll
        for (int rg = 0; rg < 16; rg++) {
          int row = ti * 32 + (rg & 3) + 8 * (rg >> 2) + 4 * ksel;
          if (row == col && row < 250) nrmsq[row] = acc[a][b2][rg];
        }
      }
    }
  }
  __syncthreads();
  if (tid < 250) {
    float s0 = sums[tid];
    float m = s0 * (1.f / 640.f);
    meanv[tid] = m;
    nrmv[tid] = nrmsq[tid] - s0 * m;
  }
  __syncthreads();

  // ---- epilogue: d2 -> 5-term gaussian kernel -> region sums
  float s_ss = 0.f, s_qq = 0.f, s_x = 0.f;
#pragma unroll
  for (int a = 0; a < 4; a++) {
    int ti = wr + 2 * a;
#pragma unroll
    for (int b2 = 0; b2 < 2; b2++) {
      int tj = wc + 4 * b2;
      int col = tj * 32 + lr;
#pragma unroll
      for (int rg = 0; rg < 16; rg++) {
        int row = ti * 32 + (rg & 3) + 8 * (rg >> 2) + 4 * ksel;
        if (row < 250 && col < 250) {
          float d2 = nrmv[row] + nrmv[col] - 2.f * acc[a][b2][rg]
                   + 1280.f * meanv[row] * meanv[col];
          d2 = fmaxf(d2, 0.f);
          float e = __expf(-0.125f * d2);
          float e2 = e * e, e4 = e2 * e2, e8 = e4 * e4, e16 = e8 * e8;
          float kv = e + e2 + e4 + e8 + e16;
          bool rs = row < 125, cs = col < 125;
          if (rs && cs)        { if (row != col) s_ss += kv; }
          else if (!rs && !cs) { if (row != col) s_qq += kv; }
          else                 s_x += kv;   // Kqs + Ksq = 2*tot(Kqs)
        }
      }
    }
  }
#pragma unroll
  for (int off = 32; off; off >>= 1) {
    s_ss += __shfl_xor(s_ss, off);
    s_qq += __shfl_xor(s_qq, off);
    s_x  += __shfl_xor(s_x, off);
  }
  if (lane == 0) { red[w * 3] = s_ss; red[w * 3 + 1] = s_qq; red[w * 3 + 2] = s_x; }
  __syncthreads();
  if (tid == 0) {
    float a = 0.f, b2 = 0.f, c = 0.f;
    for (int i = 0; i < 8; i++) { a += red[i * 3]; b2 += red[i * 3 + 1]; c += red[i * 3 + 2]; }
    mmd[(long)chunk_start * 5 + bid] = a * (1.f / 15500.f) + b2 * (1.f / 15500.f) - c * (1.f / 15625.f);
  }
}

// =====================================================================
// Kernel D: log-softmax + NLL mean
// =====================================================================
__global__ __launch_bounds__(256) void loss_kernel(const float* __restrict__ mmd,
                                                   const int* __restrict__ qy,
                                                   float* __restrict__ out) {
  __shared__ float red[256];
  int tid = threadIdx.x;
  float val = 0.f;
  if (tid < 150) {
    float l[5];
    float mx = -1e30f;
#pragma unroll
    for (int w = 0; w < 5; w++) {
      l[w] = -mmd[tid * 5 + w] * (1.0f / 12.5f);
      mx = fmaxf(mx, l[w]);
    }
    float sum = 0.f;
#pragma unroll
    for (int w = 0; w < 5; w++) sum += __expf(l[w] - mx);
    float lse = mx + logf(sum);
    int y = qy[tid];
    val = -(l[y] - lse);
  }
  red[tid] = val;
  __syncthreads();
  for (int s = 128; s > 0; s >>= 1) {
    if (tid < s) red[tid] += red[tid + s];
    __syncthreads();
  }
  if (tid == 0) out[0] = red[0] * (1.0f / 150.0f);
}

// =====================================================================
extern "C" void kernel_launch(void* const* d_in, const int* in_sizes, int n_in,
                              void* d_out, int out_size, void* d_ws, size_t ws_size,
                              hipStream_t stream) {
  (void)in_sizes; (void)n_in; (void)out_size;
  const float* sup = (const float*)d_in[0];
  const float* qry = (const float*)d_in[2];
  const int* qy = (const int*)d_in[3];
  const float* Wq = (const float*)d_in[4];
  const float* Wk = (const float*)d_in[5];
  const float* Wv = (const float*)d_in[6];
  float* ws = (float*)d_ws;
  float* X = ws + X_OFF;
  float* XT = ws + XT_OFF;
  float* proj = ws + PROJ_OFF;
  float* mmd = ws + MMD_OFF;
  unsigned short* feat = (unsigned short*)(ws + FEAT_OFF);
  float* out = (float*)d_out;

  long wsf = (long)(ws_size / 4);
  long avail_us = (wsf - FEAT_OFF) * 2;
  long chunkL = avail_us / FEAT_PER_PAIR_US;
  int chunk = (chunkL > 150) ? 150 : (chunkL < 1 ? 1 : (int)chunkL);

  hipLaunchKernelGGL(t_kernel, dim3(200), dim3(256), 0, stream, sup, qry, X, XT);
  hipLaunchKernelGGL(proj_kernel, dim3(40, 5, 3), dim3(256), 0, stream, Wq, Wk, Wv, X, proj);
  for (int c0 = 0; c0 < 150; c0 += chunk) {
    int cp = (150 - c0 < chunk) ? (150 - c0) : chunk;
    hipLaunchKernelGGL(attn_kernel, dim3(cp * 5), dim3(256), 0, stream, proj, XT, feat, c0);
    hipLaunchKernelGGL(gram_kernel, dim3(cp * 5), dim3(512), 0, stream, feat, mmd, c0);
  }
  hipLaunchKernelGGL(loss_kernel, dim3(1), dim3(256), 0, stream, mmd, qy, out);
}

// Round 5
// 535.132 us; speedup vs baseline: 8.4578x; 3.6155x over previous
//
#include <hip/hip_runtime.h>
#include <math.h>

// ---------------- problem constants ----------------
#define PP    25
#define CCH   640
#define NCOL  5000
#define SCALE_INV 0.17677669529663687f   // 1/sqrt(32)

// ---------------- workspace float offsets ----------------
#define X_OFF    0L          // [640][5000]
#define XT_OFF   3200000L    // [5000][640]
#define PROJ_OFF 6400000L    // [3][5000][640]
#define MMD_OFF  16000000L   // [750]
#define FEAT_OFF 16000768L   // bf16 region, head-blocked [way][20][250][32]
#define FEAT_PER_WAY_US 160000L   // 20*250*32
#define FEAT_PER_PAIR_US 800000L  // 5 ways

typedef __attribute__((ext_vector_type(8)))  short          s16x8;
typedef __attribute__((ext_vector_type(8)))  unsigned short u16x8;
typedef __attribute__((ext_vector_type(16))) float          f32x16;

__device__ inline unsigned short f2bf(float x) {
  unsigned u = __float_as_uint(x);
  unsigned r = u + 0x7fff + ((u >> 16) & 1);   // RNE
  return (unsigned short)(r >> 16);
}

// =====================================================================
// Kernel T: build X[c][col] and XT[col][c]
// =====================================================================
__global__ __launch_bounds__(256) void t_kernel(const float* __restrict__ sup,
                                                const float* __restrict__ qry,
                                                float* __restrict__ X,
                                                float* __restrict__ XT) {
  __shared__ float lds[16000];
  int item = blockIdx.x;
  const float* src = (item < 50) ? (sup + item * 16000) : (qry + (item - 50) * 16000);
  int tid = threadIdx.x;
  for (int e = tid * 4; e < 16000; e += 1024)
    *(float4*)&lds[e] = *(const float4*)&src[e];
  __syncthreads();
  int ibase = item * PP;
  for (int e = tid; e < 16000; e += 256) {
    int c = e / PP, p = e - c * PP;
    X[c * NCOL + ibase + p] = lds[e];
  }
  for (int e = tid * 4; e < 16000; e += 1024) {
    int p = e / CCH, c = e - p * CCH;
    float4 v;
    v.x = lds[(c + 0) * PP + p];
    v.y = lds[(c + 1) * PP + p];
    v.z = lds[(c + 2) * PP + p];
    v.w = lds[(c + 3) * PP + p];
    *(float4*)&XT[(ibase + p) * CCH + c] = v;
  }
}

// =====================================================================
// Kernel A: projections (fp32 VALU GEMM, stores out[col][o])
// =====================================================================
__global__ __launch_bounds__(256) void proj_kernel(const float* __restrict__ Wq,
                                                   const float* __restrict__ Wk,
                                                   const float* __restrict__ Wv,
                                                   const float* __restrict__ X,
                                                   float* __restrict__ proj) {
  __shared__ float At[128 * 32];
  __shared__ float Bt[32 * 128];
  int m = blockIdx.z;
  const float* W = (m == 0) ? Wq : ((m == 1) ? Wk : Wv);
  float* out = proj + (long)m * NCOL * CCH;
  int ctile = blockIdx.x * 128, otile = blockIdx.y * 128;
  int tid = threadIdx.x;
  int tr = tid >> 4, tc = tid & 15;
  float acc[8][8] = {{0.f}};

  for (int kk = 0; kk < 640; kk += 32) {
    for (int u = tid; u < 1024; u += 256) {
      int row = u >> 3, seg = u & 7;
      float4 v = *(const float4*)&W[(otile + row) * 640 + kk + seg * 4];
      *(float4*)&At[row * 32 + seg * 4] = v;
    }
    for (int u = tid; u < 1024; u += 256) {
      int k = u >> 5, seg = u & 31;
      int gc = ctile + seg * 4;
      float4 v = make_float4(0.f, 0.f, 0.f, 0.f);
      if (gc < NCOL) v = *(const float4*)&X[(kk + k) * NCOL + gc];
      *(float4*)&Bt[k * 128 + seg * 4] = v;
    }
    __syncthreads();
    for (int kc = 0; kc < 32; kc += 4) {
      float4 a[8];
#pragma unroll
      for (int i = 0; i < 8; i++) a[i] = *(float4*)&At[(tr * 8 + i) * 32 + kc];
#pragma unroll
      for (int d = 0; d < 4; d++) {
        float4 b0 = *(float4*)&Bt[(kc + d) * 128 + tc * 8];
        float4 b1 = *(float4*)&Bt[(kc + d) * 128 + tc * 8 + 4];
#pragma unroll
        for (int i = 0; i < 8; i++) {
          float av = (d == 0) ? a[i].x : (d == 1) ? a[i].y : (d == 2) ? a[i].z : a[i].w;
          acc[i][0] += av * b0.x; acc[i][1] += av * b0.y;
          acc[i][2] += av * b0.z; acc[i][3] += av * b0.w;
          acc[i][4] += av * b1.x; acc[i][5] += av * b1.y;
          acc[i][6] += av * b1.z; acc[i][7] += av * b1.w;
        }
      }
    }
    __syncthreads();
  }
#pragma unroll
  for (int jc = 0; jc < 8; jc++) {
    int col = ctile + tc * 8 + jc;
    if (col < NCOL) {
      float4 s0 = make_float4(acc[0][jc], acc[1][jc], acc[2][jc], acc[3][jc]);
      float4 s1 = make_float4(acc[4][jc], acc[5][jc], acc[6][jc], acc[7][jc]);
      *(float4*)&out[(long)col * CCH + otile + tr * 8] = s0;
      *(float4*)&out[(long)col * CCH + otile + tr * 8 + 4] = s1;
    }
  }
}

// =====================================================================
// Kernel B: MFMA attention. One wave per (pair,way,side,head), no LDS.
// S^T = K·Q^T via mfma_32x32x16 (2 K-chunks); softmax rows live per-lane
// (col q = lane&31, 16 regs + partner half = 32 m-slots, 25 valid);
// P half-swap -> A-frag of P; O = P·V via mfma; +shortcut, bf16 store.
// =====================================================================
__global__ __launch_bounds__(256) void attn_kernel(const float* __restrict__ proj,
                                                   const float* __restrict__ XT,
                                                   unsigned short* __restrict__ feat,
                                                   int chunk_start) {
  int tid = threadIdx.x, wid = tid >> 6, lane = tid & 63;
  int lr = lane & 31, hf = lane >> 5;
  int rclamp = lr > 24 ? 24 : lr;
  int bid = blockIdx.x;
  int pw = bid / 10, grp = bid - pw * 10;
  int unit = grp * 4 + wid;             // 0..39
  int side = unit >= 20 ? 1 : 0;
  int head = unit - side * 20;
  int lpi = pw / 5, way = pw - lpi * 5;
  int pair = chunk_start + lpi;
  int b = pair / 75;
  int qcol = (50 + pair) * PP;
  int sbase = (b * 25 + way * 5) * PP;
  int ho = head * 32;
  const float* Qp = proj;
  const float* Kp = proj + (long)NCOL * CCH;
  const float* Vp = proj + 2L * NCOL * CCH;
  unsigned short* fb = feat + (long)pw * FEAT_PER_WAY_US + head * 250 * 32;

  // row-fragment: lane holds X[row=lr(clamped)][ch = ho+16ks+8hf+j], j=0..7
  auto ldfrag = [&](const float* src, int col0, int ks) -> s16x8 {
    const float* p = src + (long)(col0 + rclamp) * CCH + ho + ks * 16 + hf * 8;
    float4 a = *(const float4*)p;
    float4 c = *(const float4*)(p + 4);
    s16x8 f;
    f[0] = (short)f2bf(a.x); f[1] = (short)f2bf(a.y);
    f[2] = (short)f2bf(a.z); f[3] = (short)f2bf(a.w);
    f[4] = (short)f2bf(c.x); f[5] = (short)f2bf(c.y);
    f[6] = (short)f2bf(c.z); f[7] = (short)f2bf(c.w);
    return f;
  };
  // V-fragment (B operand of PV): lane holds V[m=16ks+8hf+j][ch=ho+lr]
  auto ldvfrag = [&](const float* src, int col0, int ks) -> s16x8 {
    s16x8 f;
#pragma unroll
    for (int j = 0; j < 8; j++) {
      int m = ks * 16 + hf * 8 + j; m = m > 24 ? 24 : m;
      f[j] = (short)f2bf(src[(long)(col0 + m) * CCH + ho + lr]);
    }
    return f;
  };

  s16x8 fixA0, fixA1, fixB0, fixB1, fixV0, fixV1;
  if (side == 0) {               // sbq: Q = query item (fixed), K/V = shots
    fixB0 = ldfrag(Qp, qcol, 0); fixB1 = ldfrag(Qp, qcol, 1);
  } else {                       // qbs: K/V = query item (fixed), Q = shots
    fixA0 = ldfrag(Kp, qcol, 0); fixA1 = ldfrag(Kp, qcol, 1);
    fixV0 = ldvfrag(Vp, qcol, 0); fixV1 = ldvfrag(Vp, qcol, 1);
  }

  for (int shot = 0; shot < 5; shot++) {
    int scol = sbase + shot * PP;
    s16x8 A0, A1, B0, B1, V0, V1;
    if (side == 0) {
      A0 = ldfrag(Kp, scol, 0); A1 = ldfrag(Kp, scol, 1);
      B0 = fixB0; B1 = fixB1;
      V0 = ldvfrag(Vp, scol, 0); V1 = ldvfrag(Vp, scol, 1);
    } else {
      A0 = fixA0; A1 = fixA1;
      B0 = ldfrag(Qp, scol, 0); B1 = ldfrag(Qp, scol, 1);
      V0 = fixV0; V1 = fixV1;
    }
    // ---- S^T = K·Q^T : D[m][q], q = lr, m = (rg&3)+8*(rg>>2)+4*hf
    f32x16 s;
#pragma unroll
    for (int e = 0; e < 16; e++) s[e] = 0.f;
    s = __builtin_amdgcn_mfma_f32_32x32x16_bf16(A0, B0, s, 0, 0, 0);
    s = __builtin_amdgcn_mfma_f32_32x32x16_bf16(A1, B1, s, 0, 0, 0);
    // ---- softmax over m (rows of P) for this lane's q
    float pv[16];
    float mx = -1e30f;
#pragma unroll
    for (int rg = 0; rg < 16; rg++) {
      int m = (rg & 3) + 8 * (rg >> 2) + 4 * hf;
      float v = (m < 25) ? s[rg] : -1e30f;
      pv[rg] = v;
      mx = fmaxf(mx, v);
    }
    mx = fmaxf(mx, __shfl_xor(mx, 32));
    float sum = 0.f;
#pragma unroll
    for (int rg = 0; rg < 16; rg++) {
      float e = __expf((pv[rg] - mx) * SCALE_INV);
      pv[rg] = e;
      sum += e;
    }
    sum += __shfl_xor(sum, 32);
    float rinv = 1.f / sum;
#pragma unroll
    for (int rg = 0; rg < 16; rg++) pv[rg] *= rinv;
    // ---- build P A-frags (half-swap): frag elem j = P[q][16ks+8hf+j]
    s16x8 P0, P1;
    {
      float ex[8], fr[8];
#pragma unroll
      for (int r = 0; r < 8; r++) ex[r] = __shfl_xor(pv[r], 32);
#pragma unroll
      for (int j = 0; j < 4; j++) {
        fr[j]     = hf ? ex[4 + j] : pv[j];
        fr[4 + j] = hf ? pv[4 + j] : ex[j];
      }
#pragma unroll
      for (int j = 0; j < 8; j++) P0[j] = (short)f2bf(fr[j]);
#pragma unroll
      for (int r = 0; r < 8; r++) ex[r] = __shfl_xor(pv[8 + r], 32);
#pragma unroll
      for (int j = 0; j < 4; j++) {
        fr[j]     = hf ? ex[4 + j] : pv[8 + j];
        fr[4 + j] = hf ? pv[12 + j] : ex[j];
      }
#pragma unroll
      for (int j = 0; j < 8; j++) P1[j] = (short)f2bf(fr[j]);
    }
    // ---- O = P·V : D[q][ch], q from regs, ch = lr
    f32x16 o;
#pragma unroll
    for (int e = 0; e < 16; e++) o[e] = 0.f;
    o = __builtin_amdgcn_mfma_f32_32x32x16_bf16(P0, V0, o, 0, 0, 0);
    o = __builtin_amdgcn_mfma_f32_32x32x16_bf16(P1, V1, o, 0, 0, 0);
    // ---- + shortcut, bf16 store (head-blocked)
    int scrow = side ? qcol : scol;
    unsigned short* frow = fb + (long)((side ? 125 : 0) + shot * 25) * 32;
#pragma unroll
    for (int rg = 0; rg < 16; rg++) {
      int q = (rg & 3) + 8 * (rg >> 2) + 4 * hf;
      if (q < 25) {
        float sc = XT[(long)(scrow + q) * CCH + ho + lr];
        frow[q * 32 + lr] = f2bf(o[rg] + sc);
      }
    }
  }
}

// =====================================================================
// Kernel C: MFMA bf16 Gram (256x256, rows 0..249 = features, row 250 = ones)
// mean/norm harvested from Gram col 250 and diagonal. Head-blocked input.
// =====================================================================
__device__ inline void gram_load(u16x8* pf, const unsigned short* __restrict__ fb,
                                 int sr, int half, int kc) {
#pragma unroll
  for (int gi = 0; gi < 4; gi++) {
    u16x8 v;
    if (sr < 250) {
      v = *(const u16x8*)&fb[(long)((2 * kc + half) * 250 + sr) * 32 + gi * 8];
    } else if (sr == 250) {
#pragma unroll
      for (int e = 0; e < 8; e++) v[e] = 0x3F80;   // bf16 1.0
    } else {
#pragma unroll
      for (int e = 0; e < 8; e++) v[e] = 0;
    }
    pf[gi] = v;
  }
}

__global__ __launch_bounds__(512) void gram_kernel(const unsigned short* __restrict__ feat,
                                                   float* __restrict__ mmd,
                                                   int chunk_start) {
  __shared__ __align__(16) unsigned short tile[16384];  // 256 x 64 bf16, swizzled
  __shared__ float sums[256], nrmsq[256], meanv[256], nrmv[256];
  __shared__ float red[24];
  int bid = blockIdx.x;
  const unsigned short* fb = feat + (long)bid * FEAT_PER_WAY_US;
  int tid = threadIdx.x;
  int w = tid >> 6, lane = tid & 63;
  int wr = w >> 2, wc = w & 3;
  int lr = lane & 31, ksel = lane >> 5;
  int sr = tid >> 1, half = tid & 1;

  f32x16 acc[4][2];
#pragma unroll
  for (int a = 0; a < 4; a++)
#pragma unroll
    for (int b2 = 0; b2 < 2; b2++)
#pragma unroll
      for (int e = 0; e < 16; e++) acc[a][b2][e] = 0.f;

  u16x8 pf[4];
  gram_load(pf, fb, sr, half, 0);

  for (int kc = 0; kc < 10; kc++) {
    __syncthreads();
#pragma unroll
    for (int gi = 0; gi < 4; gi++) {
      int g = half * 4 + gi;
      *(u16x8*)&tile[sr * 64 + ((g ^ (sr & 7)) << 3)] = pf[gi];
    }
    if (kc < 9) gram_load(pf, fb, sr, half, kc + 1);
    __syncthreads();
#pragma unroll
    for (int ks = 0; ks < 4; ks++) {
      int gk = ks * 2 + ksel;
      s16x8 af[4], bfv[2];
#pragma unroll
      for (int a = 0; a < 4; a++) {
        int R = (wr + 2 * a) * 32 + lr;
        af[a] = *(const s16x8*)&tile[R * 64 + ((gk ^ (R & 7)) << 3)];
      }
#pragma unroll
      for (int b2 = 0; b2 < 2; b2++) {
        int R = (wc + 4 * b2) * 32 + lr;
        bfv[b2] = *(const s16x8*)&tile[R * 64 + ((gk ^ (R & 7)) << 3)];
      }
#pragma unroll
      for (int a = 0; a < 4; a++)
#pragma unroll
        for (int b2 = 0; b2 < 2; b2++)
          acc[a][b2] = __builtin_amdgcn_mfma_f32_32x32x16_bf16(af[a], bfv[b2], acc[a][b2], 0, 0, 0);
    }
  }

  // ---- harvest row sums (col 250) and squared norms (diagonal)
#pragma unroll
  for (int a = 0; a < 4; a++) {
    int ti = wr + 2 * a;
#pragma unroll
    for (int b2 = 0; b2 < 2; b2++) {
      int tj = wc + 4 * b2;
      int col = tj * 32 + lr;
      if (col == 250) {
#pragma unroll
        for (int rg = 0; rg < 16; rg++) {
          int row = ti * 32 + (rg & 3) + 8 * (rg >> 2) + 4 * ksel;
          if (row < 250) sums[row] = acc[a][b2][rg];
        }
      }
      if (ti == tj) {
#pragma unroll
        for (int rg = 0; rg < 16; rg++) {
          int row = ti * 32 + (rg & 3) + 8 * (rg >> 2) + 4 * ksel;
          if (row == col && row < 250) nrmsq[row] = acc[a][b2][rg];
        }
      }
    }
  }
  __syncthreads();
  if (tid < 250) {
    float s0 = sums[tid];
    float m = s0 * (1.f / 640.f);
    meanv[tid] = m;
    nrmv[tid] = nrmsq[tid] - s0 * m;
  }
  __syncthreads();

  // ---- epilogue: d2 -> 5-term gaussian kernel -> region sums
  float s_ss = 0.f, s_qq = 0.f, s_x = 0.f;
#pragma unroll
  for (int a = 0; a < 4; a++) {
    int ti = wr + 2 * a;
#pragma unroll
    for (int b2 = 0; b2 < 2; b2++) {
      int tj = wc + 4 * b2;
      int col = tj * 32 + lr;
#pragma unroll
      for (int rg = 0; rg < 16; rg++) {
        int row = ti * 32 + (rg & 3) + 8 * (rg >> 2) + 4 * ksel;
        if (row < 250 && col < 250) {
          float d2 = nrmv[row] + nrmv[col] - 2.f * acc[a][b2][rg]
                   + 1280.f * meanv[row] * meanv[col];
          d2 = fmaxf(d2, 0.f);
          float e = __expf(-0.125f * d2);
          float e2 = e * e, e4 = e2 * e2, e8 = e4 * e4, e16 = e8 * e8;
          float kv = e + e2 + e4 + e8 + e16;
          bool rs = row < 125, cs = col < 125;
          if (rs && cs)        { if (row != col) s_ss += kv; }
          else if (!rs && !cs) { if (row != col) s_qq += kv; }
          else                 s_x += kv;   // Kqs + Ksq = 2*tot(Kqs)
        }
      }
    }
  }
#pragma unroll
  for (int off = 32; off; off >>= 1) {
    s_ss += __shfl_xor(s_ss, off);
    s_qq += __shfl_xor(s_qq, off);
    s_x  += __shfl_xor(s_x, off);
  }
  if (lane == 0) { red[w * 3] = s_ss; red[w * 3 + 1] = s_qq; red[w * 3 + 2] = s_x; }
  __syncthreads();
  if (tid == 0) {
    float a = 0.f, b2 = 0.f, c = 0.f;
    for (int i = 0; i < 8; i++) { a += red[i * 3]; b2 += red[i * 3 + 1]; c += red[i * 3 + 2]; }
    mmd[(long)chunk_start * 5 + bid] = a * (1.f / 15500.f) + b2 * (1.f / 15500.f) - c * (1.f / 15625.f);
  }
}

// =====================================================================
// Kernel D: log-softmax + NLL mean
// =====================================================================
__global__ __launch_bounds__(256) void loss_kernel(const float* __restrict__ mmd,
                                                   const int* __restrict__ qy,
                                                   float* __restrict__ out) {
  __shared__ float red[256];
  int tid = threadIdx.x;
  float val = 0.f;
  if (tid < 150) {
    float l[5];
    float mx = -1e30f;
#pragma unroll
    for (int w = 0; w < 5; w++) {
      l[w] = -mmd[tid * 5 + w] * (1.0f / 12.5f);
      mx = fmaxf(mx, l[w]);
    }
    float sum = 0.f;
#pragma unroll
    for (int w = 0; w < 5; w++) sum += __expf(l[w] - mx);
    float lse = mx + logf(sum);
    int y = qy[tid];
    val = -(l[y] - lse);
  }
  red[tid] = val;
  __syncthreads();
  for (int s = 128; s > 0; s >>= 1) {
    if (tid < s) red[tid] += red[tid + s];
    __syncthreads();
  }
  if (tid == 0) out[0] = red[0] * (1.0f / 150.0f);
}

// =====================================================================
extern "C" void kernel_launch(void* const* d_in, const int* in_sizes, int n_in,
                              void* d_out, int out_size, void* d_ws, size_t ws_size,
                              hipStream_t stream) {
  (void)in_sizes; (void)n_in; (void)out_size;
  const float* sup = (const float*)d_in[0];
  const float* qry = (const float*)d_in[2];
  const int* qy = (const int*)d_in[3];
  const float* Wq = (const float*)d_in[4];
  const float* Wk = (const float*)d_in[5];
  const float* Wv = (const float*)d_in[6];
  float* ws = (float*)d_ws;
  float* X = ws + X_OFF;
  float* XT = ws + XT_OFF;
  float* proj = ws + PROJ_OFF;
  float* mmd = ws + MMD_OFF;
  unsigned short* feat = (unsigned short*)(ws + FEAT_OFF);
  float* out = (float*)d_out;

  long wsf = (long)(ws_size / 4);
  long avail_us = (wsf - FEAT_OFF) * 2;
  long chunkL = avail_us / FEAT_PER_PAIR_US;
  int chunk = (chunkL > 150) ? 150 : (chunkL < 1 ? 1 : (int)chunkL);

  hipLaunchKernelGGL(t_kernel, dim3(200), dim3(256), 0, stream, sup, qry, X, XT);
  hipLaunchKernelGGL(proj_kernel, dim3(40, 5, 3), dim3(256), 0, stream, Wq, Wk, Wv, X, proj);
  for (int c0 = 0; c0 < 150; c0 += chunk) {
    int cp = (150 - c0 < chunk) ? (150 - c0) : chunk;
    hipLaunchKernelGGL(attn_kernel, dim3(cp * 50), dim3(256), 0, stream, proj, XT, feat, c0);
    hipLaunchKernelGGL(gram_kernel, dim3(cp * 5), dim3(512), 0, stream, feat, mmd, c0);
  }
  hipLaunchKernelGGL(loss_kernel, dim3(1), dim3(256), 0, stream, mmd, qy, out);
}

// Round 6
// 342.761 us; speedup vs baseline: 13.2047x; 1.5612x over previous
//
#include <hip/hip_runtime.h>
#include <math.h>

// ---------------- problem constants ----------------
#define PP    25
#define CCH   640
#define NCOL  5000
#define SCALE_INV 0.17677669529663687f   // 1/sqrt(32)

// ---------------- workspace float offsets ----------------
#define XT_OFF   0L          // fp32 [5000][640] (shortcuts)
#define XTB_OFF  3200000L    // bf16 [5000][640] (proj B operand)
#define WB_OFF   4800000L    // bf16 [3][640][640]
#define PROJ_OFF 5414400L    // fp32 [3][5000][640], stored [col][o]
#define MMD_OFF  15014400L   // [750]
#define FEAT_OFF 15015168L   // bf16, head-blocked [way][20][250][32]
#define FEAT_PER_WAY_US 160000L
#define FEAT_PER_PAIR_US 800000L

typedef __attribute__((ext_vector_type(8)))  short          s16x8;
typedef __attribute__((ext_vector_type(8)))  unsigned short u16x8;
typedef __attribute__((ext_vector_type(4)))  unsigned short u16x4;
typedef __attribute__((ext_vector_type(16))) float          f32x16;

__device__ inline unsigned short f2bf(float x) {
  unsigned u = __float_as_uint(x);
  unsigned r = u + 0x7fff + ((u >> 16) & 1);   // RNE
  return (unsigned short)(r >> 16);
}

// =====================================================================
// Kernel T: build XT fp32 [col][c] and XTB bf16 [col][c]
// =====================================================================
__global__ __launch_bounds__(256) void t_kernel(const float* __restrict__ sup,
                                                const float* __restrict__ qry,
                                                float* __restrict__ XT,
                                                unsigned short* __restrict__ XTB) {
  __shared__ float lds[16000];
  int item = blockIdx.x;
  const float* src = (item < 50) ? (sup + item * 16000) : (qry + (item - 50) * 16000);
  int tid = threadIdx.x;
  for (int e = tid * 4; e < 16000; e += 1024)
    *(float4*)&lds[e] = *(const float4*)&src[e];
  __syncthreads();
  int ibase = item * PP;
  for (int e = tid * 4; e < 16000; e += 1024) {
    int p = e / CCH, c = e - p * CCH;
    float4 v;
    v.x = lds[(c + 0) * PP + p];
    v.y = lds[(c + 1) * PP + p];
    v.z = lds[(c + 2) * PP + p];
    v.w = lds[(c + 3) * PP + p];
    *(float4*)&XT[(long)(ibase + p) * CCH + c] = v;
    u16x4 b;
    b.x = f2bf(v.x); b.y = f2bf(v.y); b.z = f2bf(v.z); b.w = f2bf(v.w);
    *(u16x4*)&XTB[(long)(ibase + p) * CCH + c] = b;
  }
}

// =====================================================================
// Kernel W: convert Wq/Wk/Wv fp32 -> bf16 WB[3][640][640]
// =====================================================================
__global__ __launch_bounds__(256) void w_kernel(const float* __restrict__ Wq,
                                                const float* __restrict__ Wk,
                                                const float* __restrict__ Wv,
                                                unsigned short* __restrict__ WB) {
  long base = ((long)blockIdx.x * 256 + threadIdx.x) * 8;   // 600 blocks * 256 * 8 = 1228800
  int m = (int)(base / 409600L);
  long off = base - (long)m * 409600L;
  const float* W = (m == 0) ? Wq : ((m == 1) ? Wk : Wv);
  float4 a = *(const float4*)&W[off];
  float4 c = *(const float4*)&W[off + 4];
  u16x8 v;
  v[0] = f2bf(a.x); v[1] = f2bf(a.y); v[2] = f2bf(a.z); v[3] = f2bf(a.w);
  v[4] = f2bf(c.x); v[5] = f2bf(c.y); v[6] = f2bf(c.z); v[7] = f2bf(c.w);
  *(u16x8*)&WB[base] = v;
}

// =====================================================================
// Kernel A: MFMA bf16 projections. proj[m][col][o] = sum_c W[m][o][c]*XT[col][c]
// Gram-style: A rows = W rows (o), B rows = XTB rows (col). BM=BN=128, K=64.
// 512 thr / 8 waves (2x4); wave does 2x1 tiles of 32x32.
// =====================================================================
__global__ __launch_bounds__(512) void proj_kernel(const unsigned short* __restrict__ WB,
                                                   const unsigned short* __restrict__ XTB,
                                                   float* __restrict__ proj) {
  __shared__ __align__(16) unsigned short At[128 * 64];
  __shared__ __align__(16) unsigned short Bt[128 * 64];
  int m = blockIdx.z;
  int ctile = blockIdx.x * 128, otile = blockIdx.y * 128;
  const unsigned short* Wsrc = WB + (long)m * 409600L;
  float* out = proj + (long)m * NCOL * CCH;
  int tid = threadIdx.x;
  int w = tid >> 6, lane = tid & 63;
  int wr = w >> 2, wc = w & 3;
  int lr = lane & 31, ksel = lane >> 5;
  int sr = tid >> 2, sg = (tid & 3) * 2;   // staging: row, granule pair

  f32x16 acc[2];
#pragma unroll
  for (int a = 0; a < 2; a++)
#pragma unroll
    for (int e = 0; e < 16; e++) acc[a][e] = 0.f;

  int bcol = ctile + sr;
  const unsigned short* asrc = Wsrc + (long)(otile + sr) * CCH + sg * 8;
  const unsigned short* bsrc = XTB + (long)bcol * CCH + sg * 8;

  u16x8 pa[2], pb[2];
#pragma unroll
  for (int gi = 0; gi < 2; gi++) {
    pa[gi] = *(const u16x8*)&asrc[gi * 8];
    if (bcol < NCOL) pb[gi] = *(const u16x8*)&bsrc[gi * 8];
    else { u16x8 z; for (int e = 0; e < 8; e++) z[e] = 0; pb[gi] = z; }
  }

  for (int kc = 0; kc < 10; kc++) {
    __syncthreads();
#pragma unroll
    for (int gi = 0; gi < 2; gi++) {
      int g = sg + gi;
      *(u16x8*)&At[sr * 64 + ((g ^ (sr & 7)) << 3)] = pa[gi];
      *(u16x8*)&Bt[sr * 64 + ((g ^ (sr & 7)) << 3)] = pb[gi];
    }
    if (kc < 9) {
      const unsigned short* an = asrc + (kc + 1) * 64;
      const unsigned short* bn = bsrc + (kc + 1) * 64;
#pragma unroll
      for (int gi = 0; gi < 2; gi++) {
        pa[gi] = *(const u16x8*)&an[gi * 8];
        if (bcol < NCOL) pb[gi] = *(const u16x8*)&bn[gi * 8];
      }
    }
    __syncthreads();
#pragma unroll
    for (int ks = 0; ks < 4; ks++) {
      int gk = ks * 2 + ksel;
      s16x8 bf1;
      {
        int R = wc * 32 + lr;
        bf1 = *(const s16x8*)&Bt[R * 64 + ((gk ^ (R & 7)) << 3)];
      }
#pragma unroll
      for (int a = 0; a < 2; a++) {
        int R = (wr + 2 * a) * 32 + lr;
        s16x8 af = *(const s16x8*)&At[R * 64 + ((gk ^ (R & 7)) << 3)];
        acc[a] = __builtin_amdgcn_mfma_f32_32x32x16_bf16(af, bf1, acc[a], 0, 0, 0);
      }
    }
  }

  // epilogue: D[o][col]; lane col fixed, o in groups of 4 consecutive
  int col = ctile + wc * 32 + lr;
  if (col < NCOL) {
#pragma unroll
    for (int a = 0; a < 2; a++) {
      int obase = otile + (wr + 2 * a) * 32 + 4 * ksel;
#pragma unroll
      for (int g2 = 0; g2 < 4; g2++) {
        float4 v = make_float4(acc[a][g2 * 4 + 0], acc[a][g2 * 4 + 1],
                               acc[a][g2 * 4 + 2], acc[a][g2 * 4 + 3]);
        *(float4*)&out[(long)col * CCH + obase + g2 * 8] = v;
      }
    }
  }
}

// =====================================================================
// Kernel B: MFMA attention. One wave per (pair,way,side,head), no LDS.
// =====================================================================
__global__ __launch_bounds__(256) void attn_kernel(const float* __restrict__ proj,
                                                   const float* __restrict__ XT,
                                                   unsigned short* __restrict__ feat,
                                                   int chunk_start) {
  int tid = threadIdx.x, wid = tid >> 6, lane = tid & 63;
  int lr = lane & 31, hf = lane >> 5;
  int rclamp = lr > 24 ? 24 : lr;
  int bid = blockIdx.x;
  int pw = bid / 10, grp = bid - pw * 10;
  int unit = grp * 4 + wid;             // 0..39
  int side = unit >= 20 ? 1 : 0;
  int head = unit - side * 20;
  int lpi = pw / 5, way = pw - lpi * 5;
  int pair = chunk_start + lpi;
  int b = pair / 75;
  int qcol = (50 + pair) * PP;
  int sbase = (b * 25 + way * 5) * PP;
  int ho = head * 32;
  const float* Qp = proj;
  const float* Kp = proj + (long)NCOL * CCH;
  const float* Vp = proj + 2L * NCOL * CCH;
  unsigned short* fb = feat + (long)pw * FEAT_PER_WAY_US + head * 250 * 32;

  auto ldfrag = [&](const float* src, int col0, int ks) -> s16x8 {
    const float* p = src + (long)(col0 + rclamp) * CCH + ho + ks * 16 + hf * 8;
    float4 a = *(const float4*)p;
    float4 c = *(const float4*)(p + 4);
    s16x8 f;
    f[0] = (short)f2bf(a.x); f[1] = (short)f2bf(a.y);
    f[2] = (short)f2bf(a.z); f[3] = (short)f2bf(a.w);
    f[4] = (short)f2bf(c.x); f[5] = (short)f2bf(c.y);
    f[6] = (short)f2bf(c.z); f[7] = (short)f2bf(c.w);
    return f;
  };
  auto ldvfrag = [&](const float* src, int col0, int ks) -> s16x8 {
    s16x8 f;
#pragma unroll
    for (int j = 0; j < 8; j++) {
      int m = ks * 16 + hf * 8 + j; m = m > 24 ? 24 : m;
      f[j] = (short)f2bf(src[(long)(col0 + m) * CCH + ho + lr]);
    }
    return f;
  };

  s16x8 fixA0, fixA1, fixB0, fixB1, fixV0, fixV1;
  if (side == 0) {
    fixB0 = ldfrag(Qp, qcol, 0); fixB1 = ldfrag(Qp, qcol, 1);
  } else {
    fixA0 = ldfrag(Kp, qcol, 0); fixA1 = ldfrag(Kp, qcol, 1);
    fixV0 = ldvfrag(Vp, qcol, 0); fixV1 = ldvfrag(Vp, qcol, 1);
  }

  for (int shot = 0; shot < 5; shot++) {
    int scol = sbase + shot * PP;
    s16x8 A0, A1, B0, B1, V0, V1;
    if (side == 0) {
      A0 = ldfrag(Kp, scol, 0); A1 = ldfrag(Kp, scol, 1);
      B0 = fixB0; B1 = fixB1;
      V0 = ldvfrag(Vp, scol, 0); V1 = ldvfrag(Vp, scol, 1);
    } else {
      A0 = fixA0; A1 = fixA1;
      B0 = ldfrag(Qp, scol, 0); B1 = ldfrag(Qp, scol, 1);
      V0 = fixV0; V1 = fixV1;
    }
    f32x16 s;
#pragma unroll
    for (int e = 0; e < 16; e++) s[e] = 0.f;
    s = __builtin_amdgcn_mfma_f32_32x32x16_bf16(A0, B0, s, 0, 0, 0);
    s = __builtin_amdgcn_mfma_f32_32x32x16_bf16(A1, B1, s, 0, 0, 0);
    float pv[16];
    float mx = -1e30f;
#pragma unroll
    for (int rg = 0; rg < 16; rg++) {
      int mm = (rg & 3) + 8 * (rg >> 2) + 4 * hf;
      float v = (mm < 25) ? s[rg] : -1e30f;
      pv[rg] = v;
      mx = fmaxf(mx, v);
    }
    mx = fmaxf(mx, __shfl_xor(mx, 32));
    float sum = 0.f;
#pragma unroll
    for (int rg = 0; rg < 16; rg++) {
      float e = __expf((pv[rg] - mx) * SCALE_INV);
      pv[rg] = e;
      sum += e;
    }
    sum += __shfl_xor(sum, 32);
    float rinv = 1.f / sum;
#pragma unroll
    for (int rg = 0; rg < 16; rg++) pv[rg] *= rinv;
    s16x8 P0, P1;
    {
      float ex[8], fr[8];
#pragma unroll
      for (int r = 0; r < 8; r++) ex[r] = __shfl_xor(pv[r], 32);
#pragma unroll
      for (int j = 0; j < 4; j++) {
        fr[j]     = hf ? ex[4 + j] : pv[j];
        fr[4 + j] = hf ? pv[4 + j] : ex[j];
      }
#pragma unroll
      for (int j = 0; j < 8; j++) P0[j] = (short)f2bf(fr[j]);
#pragma unroll
      for (int r = 0; r < 8; r++) ex[r] = __shfl_xor(pv[8 + r], 32);
#pragma unroll
      for (int j = 0; j < 4; j++) {
        fr[j]     = hf ? ex[4 + j] : pv[8 + j];
        fr[4 + j] = hf ? pv[12 + j] : ex[j];
      }
#pragma unroll
      for (int j = 0; j < 8; j++) P1[j] = (short)f2bf(fr[j]);
    }
    f32x16 o;
#pragma unroll
    for (int e = 0; e < 16; e++) o[e] = 0.f;
    o = __builtin_amdgcn_mfma_f32_32x32x16_bf16(P0, V0, o, 0, 0, 0);
    o = __builtin_amdgcn_mfma_f32_32x32x16_bf16(P1, V1, o, 0, 0, 0);
    int scrow = side ? qcol : scol;
    unsigned short* frow = fb + (long)((side ? 125 : 0) + shot * 25) * 32;
#pragma unroll
    for (int rg = 0; rg < 16; rg++) {
      int q = (rg & 3) + 8 * (rg >> 2) + 4 * hf;
      if (q < 25) {
        float sc = XT[(long)(scrow + q) * CCH + ho + lr];
        frow[q * 32 + lr] = f2bf(o[rg] + sc);
      }
    }
  }
}

// =====================================================================
// Kernel C: MFMA bf16 Gram (rows 0..249 features, row 250 = ones)
// =====================================================================
__device__ inline void gram_load(u16x8* pf, const unsigned short* __restrict__ fb,
                                 int sr, int half, int kc) {
#pragma unroll
  for (int gi = 0; gi < 4; gi++) {
    u16x8 v;
    if (sr < 250) {
      v = *(const u16x8*)&fb[(long)((2 * kc + half) * 250 + sr) * 32 + gi * 8];
    } else if (sr == 250) {
#pragma unroll
      for (int e = 0; e < 8; e++) v[e] = 0x3F80;
    } else {
#pragma unroll
      for (int e = 0; e < 8; e++) v[e] = 0;
    }
    pf[gi] = v;
  }
}

__global__ __launch_bounds__(512) void gram_kernel(const unsigned short* __restrict__ feat,
                                                   float* __restrict__ mmd,
                                                   int chunk_start) {
  __shared__ __align__(16) unsigned short tile[16384];
  __shared__ float sums[256], nrmsq[256], meanv[256], nrmv[256];
  __shared__ float red[24];
  int bid = blockIdx.x;
  const unsigned short* fb = feat + (long)bid * FEAT_PER_WAY_US;
  int tid = threadIdx.x;
  int w = tid >> 6, lane = tid & 63;
  int wr = w >> 2, wc = w & 3;
  int lr = lane & 31, ksel = lane >> 5;
  int sr = tid >> 1, half = tid & 1;

  f32x16 acc[4][2];
#pragma unroll
  for (int a = 0; a < 4; a++)
#pragma unroll
    for (int b2 = 0; b2 < 2; b2++)
#pragma unroll
      for (int e = 0; e < 16; e++) acc[a][b2][e] = 0.f;

  u16x8 pf[4];
  gram_load(pf, fb, sr, half, 0);

  for (int kc = 0; kc < 10; kc++) {
    __syncthreads();
#pragma unroll
    for (int gi = 0; gi < 4; gi++) {
      int g = half * 4 + gi;
      *(u16x8*)&tile[sr * 64 + ((g ^ (sr & 7)) << 3)] = pf[gi];
    }
    if (kc < 9) gram_load(pf, fb, sr, half, kc + 1);
    __syncthreads();
#pragma unroll
    for (int ks = 0; ks < 4; ks++) {
      int gk = ks * 2 + ksel;
      s16x8 af[4], bfv[2];
#pragma unroll
      for (int a = 0; a < 4; a++) {
        int R = (wr + 2 * a) * 32 + lr;
        af[a] = *(const s16x8*)&tile[R * 64 + ((gk ^ (R & 7)) << 3)];
      }
#pragma unroll
      for (int b2 = 0; b2 < 2; b2++) {
        int R = (wc + 4 * b2) * 32 + lr;
        bfv[b2] = *(const s16x8*)&tile[R * 64 + ((gk ^ (R & 7)) << 3)];
      }
#pragma unroll
      for (int a = 0; a < 4; a++)
#pragma unroll
        for (int b2 = 0; b2 < 2; b2++)
          acc[a][b2] = __builtin_amdgcn_mfma_f32_32x32x16_bf16(af[a], bfv[b2], acc[a][b2], 0, 0, 0);
    }
  }

#pragma unroll
  for (int a = 0; a < 4; a++) {
    int ti = wr + 2 * a;
#pragma unroll
    for (int b2 = 0; b2 < 2; b2++) {
      int tj = wc + 4 * b2;
      int col = tj * 32 + lr;
      if (col == 250) {
#pragma unroll
        for (int rg = 0; rg < 16; rg++) {
          int row = ti * 32 + (rg & 3) + 8 * (rg >> 2) + 4 * ksel;
          if (row < 250) sums[row] = acc[a][b2][rg];
        }
      }
      if (ti == tj) {
#pragma unroll
        for (int rg = 0; rg < 16; rg++) {
          int row = ti * 32 + (rg & 3) + 8 * (rg >> 2) + 4 * ksel;
          if (row == col && row < 250) nrmsq[row] = acc[a][b2][rg];
        }
      }
    }
  }
  __syncthreads();
  if (tid < 250) {
    float s0 = sums[tid];
    float m = s0 * (1.f / 640.f);
    meanv[tid] = m;
    nrmv[tid] = nrmsq[tid] - s0 * m;
  }
  __syncthreads();

  float s_ss = 0.f, s_qq = 0.f, s_x = 0.f;
#pragma unroll
  for (int a = 0; a < 4; a++) {
    int ti = wr + 2 * a;
#pragma unroll
    for (int b2 = 0; b2 < 2; b2++) {
      int tj = wc + 4 * b2;
      int col = tj * 32 + lr;
#pragma unroll
      for (int rg = 0; rg < 16; rg++) {
        int row = ti * 32 + (rg & 3) + 8 * (rg >> 2) + 4 * ksel;
        if (row < 250 && col < 250) {
          float d2 = nrmv[row] + nrmv[col] - 2.f * acc[a][b2][rg]
                   + 1280.f * meanv[row] * meanv[col];
          d2 = fmaxf(d2, 0.f);
          float e = __expf(-0.125f * d2);
          float e2 = e * e, e4 = e2 * e2, e8 = e4 * e4, e16 = e8 * e8;
          float kv = e + e2 + e4 + e8 + e16;
          bool rs = row < 125, cs = col < 125;
          if (rs && cs)        { if (row != col) s_ss += kv; }
          else if (!rs && !cs) { if (row != col) s_qq += kv; }
          else                 s_x += kv;
        }
      }
    }
  }
#pragma unroll
  for (int off = 32; off; off >>= 1) {
    s_ss += __shfl_xor(s_ss, off);
    s_qq += __shfl_xor(s_qq, off);
    s_x  += __shfl_xor(s_x, off);
  }
  if (lane == 0) { red[w * 3] = s_ss; red[w * 3 + 1] = s_qq; red[w * 3 + 2] = s_x; }
  __syncthreads();
  if (tid == 0) {
    float a = 0.f, b2 = 0.f, c = 0.f;
    for (int i = 0; i < 8; i++) { a += red[i * 3]; b2 += red[i * 3 + 1]; c += red[i * 3 + 2]; }
    mmd[(long)chunk_start * 5 + bid] = a * (1.f / 15500.f) + b2 * (1.f / 15500.f) - c * (1.f / 15625.f);
  }
}

// =====================================================================
// Kernel D: log-softmax + NLL mean
// =====================================================================
__global__ __launch_bounds__(256) void loss_kernel(const float* __restrict__ mmd,
                                                   const int* __restrict__ qy,
                                                   float* __restrict__ out) {
  __shared__ float red[256];
  int tid = threadIdx.x;
  float val = 0.f;
  if (tid < 150) {
    float l[5];
    float mx = -1e30f;
#pragma unroll
    for (int w = 0; w < 5; w++) {
      l[w] = -mmd[tid * 5 + w] * (1.0f / 12.5f);
      mx = fmaxf(mx, l[w]);
    }
    float sum = 0.f;
#pragma unroll
    for (int w = 0; w < 5; w++) sum += __expf(l[w] - mx);
    float lse = mx + logf(sum);
    int y = qy[tid];
    val = -(l[y] - lse);
  }
  red[tid] = val;
  __syncthreads();
  for (int s = 128; s > 0; s >>= 1) {
    if (tid < s) red[tid] += red[tid + s];
    __syncthreads();
  }
  if (tid == 0) out[0] = red[0] * (1.0f / 150.0f);
}

// =====================================================================
extern "C" void kernel_launch(void* const* d_in, const int* in_sizes, int n_in,
                              void* d_out, int out_size, void* d_ws, size_t ws_size,
                              hipStream_t stream) {
  (void)in_sizes; (void)n_in; (void)out_size;
  const float* sup = (const float*)d_in[0];
  const float* qry = (const float*)d_in[2];
  const int* qy = (const int*)d_in[3];
  const float* Wq = (const float*)d_in[4];
  const float* Wk = (const float*)d_in[5];
  const float* Wv = (const float*)d_in[6];
  float* ws = (float*)d_ws;
  float* XT = ws + XT_OFF;
  unsigned short* XTB = (unsigned short*)(ws + XTB_OFF);
  unsigned short* WB = (unsigned short*)(ws + WB_OFF);
  float* proj = ws + PROJ_OFF;
  float* mmd = ws + MMD_OFF;
  unsigned short* feat = (unsigned short*)(ws + FEAT_OFF);
  float* out = (float*)d_out;

  long wsf = (long)(ws_size / 4);
  long avail_us = (wsf - FEAT_OFF) * 2;
  long chunkL = avail_us / FEAT_PER_PAIR_US;
  int chunk = (chunkL > 150) ? 150 : (chunkL < 1 ? 1 : (int)chunkL);

  hipLaunchKernelGGL(t_kernel, dim3(200), dim3(256), 0, stream, sup, qry, XT, XTB);
  hipLaunchKernelGGL(w_kernel, dim3(600), dim3(256), 0, stream, Wq, Wk, Wv, WB);
  hipLaunchKernelGGL(proj_kernel, dim3(40, 5, 3), dim3(512), 0, stream, WB, XTB, proj);
  for (int c0 = 0; c0 < 150; c0 += chunk) {
    int cp = (150 - c0 < chunk) ? (150 - c0) : chunk;
    hipLaunchKernelGGL(attn_kernel, dim3(cp * 50), dim3(256), 0, stream, proj, XT, feat, c0);
    hipLaunchKernelGGL(gram_kernel, dim3(cp * 5), dim3(512), 0, stream, feat, mmd, c0);
  }
  hipLaunchKernelGGL(loss_kernel, dim3(1), dim3(256), 0, stream, mmd, qy, out);
}

// Round 7
// 271.599 us; speedup vs baseline: 16.6645x; 1.2620x over previous
//
#include <hip/hip_runtime.h>
#include <math.h>

// ---------------- problem constants ----------------
#define PP    25
#define CCH   640
#define NCOL  5000
#define SCALE_INV 0.17677669529663687f   // 1/sqrt(32)

// ---------------- workspace float offsets ----------------
#define XTB_OFF   0L         // bf16 [5000][640]  (shortcuts + proj B operand)
#define WB_OFF    1600000L   // bf16 [3][640][640]
#define PROJB_OFF 2214400L   // bf16 [3][5000][640], stored [col][o]
#define MMD_OFF   7014400L   // [750]
#define FEAT_OFF  7015168L   // bf16, head-blocked [way][20][250][32]
#define FEAT_PER_WAY_US 160000L
#define FEAT_PER_PAIR_US 800000L

typedef __attribute__((ext_vector_type(8)))  short          s16x8;
typedef __attribute__((ext_vector_type(8)))  unsigned short u16x8;
typedef __attribute__((ext_vector_type(4)))  unsigned short u16x4;
typedef __attribute__((ext_vector_type(16))) float          f32x16;

__device__ inline unsigned short f2bf(float x) {
  unsigned u = __float_as_uint(x);
  unsigned r = u + 0x7fff + ((u >> 16) & 1);   // RNE
  return (unsigned short)(r >> 16);
}
__device__ inline float bf2f(unsigned short b) {
  return __uint_as_float(((unsigned)b) << 16);
}

// =====================================================================
// Kernel T: build XTB bf16 [col][c] (item-major transposed input)
// =====================================================================
__global__ __launch_bounds__(256) void t_kernel(const float* __restrict__ sup,
                                                const float* __restrict__ qry,
                                                unsigned short* __restrict__ XTB) {
  __shared__ float lds[16000];
  int item = blockIdx.x;
  const float* src = (item < 50) ? (sup + item * 16000) : (qry + (item - 50) * 16000);
  int tid = threadIdx.x;
  for (int e = tid * 4; e < 16000; e += 1024)
    *(float4*)&lds[e] = *(const float4*)&src[e];
  __syncthreads();
  int ibase = item * PP;
  for (int e = tid * 4; e < 16000; e += 1024) {
    int p = e / CCH, c = e - p * CCH;
    u16x4 b;
    b.x = f2bf(lds[(c + 0) * PP + p]);
    b.y = f2bf(lds[(c + 1) * PP + p]);
    b.z = f2bf(lds[(c + 2) * PP + p]);
    b.w = f2bf(lds[(c + 3) * PP + p]);
    *(u16x4*)&XTB[(long)(ibase + p) * CCH + c] = b;
  }
}

// =====================================================================
// Kernel W: convert Wq/Wk/Wv fp32 -> bf16 WB[3][640][640]
// =====================================================================
__global__ __launch_bounds__(256) void w_kernel(const float* __restrict__ Wq,
                                                const float* __restrict__ Wk,
                                                const float* __restrict__ Wv,
                                                unsigned short* __restrict__ WB) {
  long base = ((long)blockIdx.x * 256 + threadIdx.x) * 8;
  int m = (int)(base / 409600L);
  long off = base - (long)m * 409600L;
  const float* W = (m == 0) ? Wq : ((m == 1) ? Wk : Wv);
  float4 a = *(const float4*)&W[off];
  float4 c = *(const float4*)&W[off + 4];
  u16x8 v;
  v[0] = f2bf(a.x); v[1] = f2bf(a.y); v[2] = f2bf(a.z); v[3] = f2bf(a.w);
  v[4] = f2bf(c.x); v[5] = f2bf(c.y); v[6] = f2bf(c.z); v[7] = f2bf(c.w);
  *(u16x8*)&WB[base] = v;
}

// =====================================================================
// Kernel A: MFMA bf16 projections -> bf16 out. BM=BN=128, K-chunks of 64.
// =====================================================================
__global__ __launch_bounds__(512) void proj_kernel(const unsigned short* __restrict__ WB,
                                                   const unsigned short* __restrict__ XTB,
                                                   unsigned short* __restrict__ proj) {
  __shared__ __align__(16) unsigned short At[128 * 64];
  __shared__ __align__(16) unsigned short Bt[128 * 64];
  int m = blockIdx.z;
  int ctile = blockIdx.x * 128, otile = blockIdx.y * 128;
  const unsigned short* Wsrc = WB + (long)m * 409600L;
  unsigned short* out = proj + (long)m * NCOL * CCH;
  int tid = threadIdx.x;
  int w = tid >> 6, lane = tid & 63;
  int wr = w >> 2, wc = w & 3;
  int lr = lane & 31, ksel = lane >> 5;
  int sr = tid >> 2, sg = (tid & 3) * 2;

  f32x16 acc[2];
#pragma unroll
  for (int a = 0; a < 2; a++)
#pragma unroll
    for (int e = 0; e < 16; e++) acc[a][e] = 0.f;

  int bcol = ctile + sr;
  const unsigned short* asrc = Wsrc + (long)(otile + sr) * CCH + sg * 8;
  const unsigned short* bsrc = XTB + (long)bcol * CCH + sg * 8;

  u16x8 pa[2], pb[2];
#pragma unroll
  for (int gi = 0; gi < 2; gi++) {
    pa[gi] = *(const u16x8*)&asrc[gi * 8];
    if (bcol < NCOL) pb[gi] = *(const u16x8*)&bsrc[gi * 8];
    else { u16x8 z; for (int e = 0; e < 8; e++) z[e] = 0; pb[gi] = z; }
  }

  for (int kc = 0; kc < 10; kc++) {
    __syncthreads();
#pragma unroll
    for (int gi = 0; gi < 2; gi++) {
      int g = sg + gi;
      *(u16x8*)&At[sr * 64 + ((g ^ (sr & 7)) << 3)] = pa[gi];
      *(u16x8*)&Bt[sr * 64 + ((g ^ (sr & 7)) << 3)] = pb[gi];
    }
    if (kc < 9) {
      const unsigned short* an = asrc + (kc + 1) * 64;
      const unsigned short* bn = bsrc + (kc + 1) * 64;
#pragma unroll
      for (int gi = 0; gi < 2; gi++) {
        pa[gi] = *(const u16x8*)&an[gi * 8];
        if (bcol < NCOL) pb[gi] = *(const u16x8*)&bn[gi * 8];
      }
    }
    __syncthreads();
#pragma unroll
    for (int ks = 0; ks < 4; ks++) {
      int gk = ks * 2 + ksel;
      s16x8 bf1;
      {
        int R = wc * 32 + lr;
        bf1 = *(const s16x8*)&Bt[R * 64 + ((gk ^ (R & 7)) << 3)];
      }
#pragma unroll
      for (int a = 0; a < 2; a++) {
        int R = (wr + 2 * a) * 32 + lr;
        s16x8 af = *(const s16x8*)&At[R * 64 + ((gk ^ (R & 7)) << 3)];
        acc[a] = __builtin_amdgcn_mfma_f32_32x32x16_bf16(af, bf1, acc[a], 0, 0, 0);
      }
    }
  }

  int col = ctile + wc * 32 + lr;
  if (col < NCOL) {
#pragma unroll
    for (int a = 0; a < 2; a++) {
      int obase = otile + (wr + 2 * a) * 32 + 4 * ksel;
#pragma unroll
      for (int g2 = 0; g2 < 4; g2++) {
        u16x4 v;
        v.x = f2bf(acc[a][g2 * 4 + 0]);
        v.y = f2bf(acc[a][g2 * 4 + 1]);
        v.z = f2bf(acc[a][g2 * 4 + 2]);
        v.w = f2bf(acc[a][g2 * 4 + 3]);
        *(u16x4*)&out[(long)col * CCH + obase + g2 * 8] = v;
      }
    }
  }
}

// =====================================================================
// Kernel B: MFMA attention, bf16 operands straight from memory.
// One wave per (pair,way,side,head), no LDS.
// =====================================================================
__global__ __launch_bounds__(256) void attn_kernel(const unsigned short* __restrict__ proj,
                                                   const unsigned short* __restrict__ XTB,
                                                   unsigned short* __restrict__ feat,
                                                   int chunk_start) {
  int tid = threadIdx.x, wid = tid >> 6, lane = tid & 63;
  int lr = lane & 31, hf = lane >> 5;
  int rclamp = lr > 24 ? 24 : lr;
  int bid = blockIdx.x;
  int pw = bid / 10, grp = bid - pw * 10;
  int unit = grp * 4 + wid;
  int side = unit >= 20 ? 1 : 0;
  int head = unit - side * 20;
  int lpi = pw / 5, way = pw - lpi * 5;
  int pair = chunk_start + lpi;
  int b = pair / 75;
  int qcol = (50 + pair) * PP;
  int sbase = (b * 25 + way * 5) * PP;
  int ho = head * 32;
  const unsigned short* Qp = proj;
  const unsigned short* Kp = proj + (long)NCOL * CCH;
  const unsigned short* Vp = proj + 2L * NCOL * CCH;
  unsigned short* fb = feat + (long)pw * FEAT_PER_WAY_US + head * 250 * 32;

  // row-fragment: lane holds X[row=lr(clamped)][ch = ho+16ks+8hf+j], one 16B load
  auto ldfrag = [&](const unsigned short* src, int col0, int ks) -> s16x8 {
    return *(const s16x8*)&src[(long)(col0 + rclamp) * CCH + ho + ks * 16 + hf * 8];
  };
  // V-fragment (B operand of PV): lane holds V[m=16ks+8hf+j][ch=ho+lr]
  auto ldvfrag = [&](const unsigned short* src, int col0, int ks) -> s16x8 {
    s16x8 f;
#pragma unroll
    for (int j = 0; j < 8; j++) {
      int m = ks * 16 + hf * 8 + j; m = m > 24 ? 24 : m;
      f[j] = (short)src[(long)(col0 + m) * CCH + ho + lr];
    }
    return f;
  };

  s16x8 fixA0, fixA1, fixB0, fixB1, fixV0, fixV1;
  if (side == 0) {               // sbq: Q = query item fixed
    fixB0 = ldfrag(Qp, qcol, 0); fixB1 = ldfrag(Qp, qcol, 1);
  } else {                       // qbs: K/V = query item fixed
    fixA0 = ldfrag(Kp, qcol, 0); fixA1 = ldfrag(Kp, qcol, 1);
    fixV0 = ldvfrag(Vp, qcol, 0); fixV1 = ldvfrag(Vp, qcol, 1);
  }

  for (int shot = 0; shot < 5; shot++) {
    int scol = sbase + shot * PP;
    s16x8 A0, A1, B0, B1, V0, V1;
    if (side == 0) {
      A0 = ldfrag(Kp, scol, 0); A1 = ldfrag(Kp, scol, 1);
      B0 = fixB0; B1 = fixB1;
      V0 = ldvfrag(Vp, scol, 0); V1 = ldvfrag(Vp, scol, 1);
    } else {
      A0 = fixA0; A1 = fixA1;
      B0 = ldfrag(Qp, scol, 0); B1 = ldfrag(Qp, scol, 1);
      V0 = fixV0; V1 = fixV1;
    }
    // S^T = K·Q^T : D[m][q], q = lr
    f32x16 s;
#pragma unroll
    for (int e = 0; e < 16; e++) s[e] = 0.f;
    s = __builtin_amdgcn_mfma_f32_32x32x16_bf16(A0, B0, s, 0, 0, 0);
    s = __builtin_amdgcn_mfma_f32_32x32x16_bf16(A1, B1, s, 0, 0, 0);
    // softmax over m for this lane's q
    float pv[16];
    float mx = -1e30f;
#pragma unroll
    for (int rg = 0; rg < 16; rg++) {
      int mm = (rg & 3) + 8 * (rg >> 2) + 4 * hf;
      float v = (mm < 25) ? s[rg] : -1e30f;
      pv[rg] = v;
      mx = fmaxf(mx, v);
    }
    mx = fmaxf(mx, __shfl_xor(mx, 32));
    float sum = 0.f;
#pragma unroll
    for (int rg = 0; rg < 16; rg++) {
      float e = __expf((pv[rg] - mx) * SCALE_INV);
      pv[rg] = e;
      sum += e;
    }
    sum += __shfl_xor(sum, 32);
    float rinv = 1.f / sum;
#pragma unroll
    for (int rg = 0; rg < 16; rg++) pv[rg] *= rinv;
    // P A-frags (half-swap)
    s16x8 P0, P1;
    {
      float ex[8], fr[8];
#pragma unroll
      for (int r = 0; r < 8; r++) ex[r] = __shfl_xor(pv[r], 32);
#pragma unroll
      for (int j = 0; j < 4; j++) {
        fr[j]     = hf ? ex[4 + j] : pv[j];
        fr[4 + j] = hf ? pv[4 + j] : ex[j];
      }
#pragma unroll
      for (int j = 0; j < 8; j++) P0[j] = (short)f2bf(fr[j]);
#pragma unroll
      for (int r = 0; r < 8; r++) ex[r] = __shfl_xor(pv[8 + r], 32);
#pragma unroll
      for (int j = 0; j < 4; j++) {
        fr[j]     = hf ? ex[4 + j] : pv[8 + j];
        fr[4 + j] = hf ? pv[12 + j] : ex[j];
      }
#pragma unroll
      for (int j = 0; j < 8; j++) P1[j] = (short)f2bf(fr[j]);
    }
    // O = P·V
    f32x16 o;
#pragma unroll
    for (int e = 0; e < 16; e++) o[e] = 0.f;
    o = __builtin_amdgcn_mfma_f32_32x32x16_bf16(P0, V0, o, 0, 0, 0);
    o = __builtin_amdgcn_mfma_f32_32x32x16_bf16(P1, V1, o, 0, 0, 0);
    // + shortcut (bf16), bf16 store
    int scrow = side ? qcol : scol;
    unsigned short* frow = fb + (long)((side ? 125 : 0) + shot * 25) * 32;
#pragma unroll
    for (int rg = 0; rg < 16; rg++) {
      int q = (rg & 3) + 8 * (rg >> 2) + 4 * hf;
      if (q < 25) {
        float sc = bf2f(XTB[(long)(scrow + q) * CCH + ho + lr]);
        frow[q * 32 + lr] = f2bf(o[rg] + sc);
      }
    }
  }
}

// =====================================================================
// Kernel C: MFMA bf16 Gram (rows 0..249 features, row 250 = ones)
// =====================================================================
__device__ inline void gram_load(u16x8* pf, const unsigned short* __restrict__ fb,
                                 int sr, int half, int kc) {
#pragma unroll
  for (int gi = 0; gi < 4; gi++) {
    u16x8 v;
    if (sr < 250) {
      v = *(const u16x8*)&fb[(long)((2 * kc + half) * 250 + sr) * 32 + gi * 8];
    } else if (sr == 250) {
#pragma unroll
      for (int e = 0; e < 8; e++) v[e] = 0x3F80;
    } else {
#pragma unroll
      for (int e = 0; e < 8; e++) v[e] = 0;
    }
    pf[gi] = v;
  }
}

__global__ __launch_bounds__(512) void gram_kernel(const unsigned short* __restrict__ feat,
                                                   float* __restrict__ mmd,
                                                   int chunk_start) {
  __shared__ __align__(16) unsigned short tile[16384];
  __shared__ float sums[256], nrmsq[256], meanv[256], nrmv[256];
  __shared__ float red[24];
  int bid = blockIdx.x;
  const unsigned short* fb = feat + (long)bid * FEAT_PER_WAY_US;
  int tid = threadIdx.x;
  int w = tid >> 6, lane = tid & 63;
  int wr = w >> 2, wc = w & 3;
  int lr = lane & 31, ksel = lane >> 5;
  int sr = tid >> 1, half = tid & 1;

  f32x16 acc[4][2];
#pragma unroll
  for (int a = 0; a < 4; a++)
#pragma unroll
    for (int b2 = 0; b2 < 2; b2++)
#pragma unroll
      for (int e = 0; e < 16; e++) acc[a][b2][e] = 0.f;

  u16x8 pf[4];
  gram_load(pf, fb, sr, half, 0);

  for (int kc = 0; kc < 10; kc++) {
    __syncthreads();
#pragma unroll
    for (int gi = 0; gi < 4; gi++) {
      int g = half * 4 + gi;
      *(u16x8*)&tile[sr * 64 + ((g ^ (sr & 7)) << 3)] = pf[gi];
    }
    if (kc < 9) gram_load(pf, fb, sr, half, kc + 1);
    __syncthreads();
#pragma unroll
    for (int ks = 0; ks < 4; ks++) {
      int gk = ks * 2 + ksel;
      s16x8 af[4], bfv[2];
#pragma unroll
      for (int a = 0; a < 4; a++) {
        int R = (wr + 2 * a) * 32 + lr;
        af[a] = *(const s16x8*)&tile[R * 64 + ((gk ^ (R & 7)) << 3)];
      }
#pragma unroll
      for (int b2 = 0; b2 < 2; b2++) {
        int R = (wc + 4 * b2) * 32 + lr;
        bfv[b2] = *(const s16x8*)&tile[R * 64 + ((gk ^ (R & 7)) << 3)];
      }
#pragma unroll
      for (int a = 0; a < 4; a++)
#pragma unroll
        for (int b2 = 0; b2 < 2; b2++)
          acc[a][b2] = __builtin_amdgcn_mfma_f32_32x32x16_bf16(af[a], bfv[b2], acc[a][b2], 0, 0, 0);
    }
  }

#pragma unroll
  for (int a = 0; a < 4; a++) {
    int ti = wr + 2 * a;
#pragma unroll
    for (int b2 = 0; b2 < 2; b2++) {
      int tj = wc + 4 * b2;
      int col = tj * 32 + lr;
      if (col == 250) {
#pragma unroll
        for (int rg = 0; rg < 16; rg++) {
          int row = ti * 32 + (rg & 3) + 8 * (rg >> 2) + 4 * ksel;
          if (row < 250) sums[row] = acc[a][b2][rg];
        }
      }
      if (ti == tj) {
#pragma unroll
        for (int rg = 0; rg < 16; rg++) {
          int row = ti * 32 + (rg & 3) + 8 * (rg >> 2) + 4 * ksel;
          if (row == col && row < 250) nrmsq[row] = acc[a][b2][rg];
        }
      }
    }
  }
  __syncthreads();
  if (tid < 250) {
    float s0 = sums[tid];
    float m = s0 * (1.f / 640.f);
    meanv[tid] = m;
    nrmv[tid] = nrmsq[tid] - s0 * m;
  }
  __syncthreads();

  float s_ss = 0.f, s_qq = 0.f, s_x = 0.f;
#pragma unroll
  for (int a = 0; a < 4; a++) {
    int ti = wr + 2 * a;
#pragma unroll
    for (int b2 = 0; b2 < 2; b2++) {
      int tj = wc + 4 * b2;
      int col = tj * 32 + lr;
#pragma unroll
      for (int rg = 0; rg < 16; rg++) {
        int row = ti * 32 + (rg & 3) + 8 * (rg >> 2) + 4 * ksel;
        if (row < 250 && col < 250) {
          float d2 = nrmv[row] + nrmv[col] - 2.f * acc[a][b2][rg]
                   + 1280.f * meanv[row] * meanv[col];
          d2 = fmaxf(d2, 0.f);
          float e = __expf(-0.125f * d2);
          float e2 = e * e, e4 = e2 * e2, e8 = e4 * e4, e16 = e8 * e8;
          float kv = e + e2 + e4 + e8 + e16;
          bool rs = row < 125, cs = col < 125;
          if (rs && cs)        { if (row != col) s_ss += kv; }
          else if (!rs && !cs) { if (row != col) s_qq += kv; }
          else                 s_x += kv;
        }
      }
    }
  }
#pragma unroll
  for (int off = 32; off; off >>= 1) {
    s_ss += __shfl_xor(s_ss, off);
    s_qq += __shfl_xor(s_qq, off);
    s_x  += __shfl_xor(s_x, off);
  }
  if (lane == 0) { red[w * 3] = s_ss; red[w * 3 + 1] = s_qq; red[w * 3 + 2] = s_x; }
  __syncthreads();
  if (tid == 0) {
    float a = 0.f, b2 = 0.f, c = 0.f;
    for (int i = 0; i < 8; i++) { a += red[i * 3]; b2 += red[i * 3 + 1]; c += red[i * 3 + 2]; }
    mmd[(long)chunk_start * 5 + bid] = a * (1.f / 15500.f) + b2 * (1.f / 15500.f) - c * (1.f / 15625.f);
  }
}

// =====================================================================
// Kernel D: log-softmax + NLL mean
// =====================================================================
__global__ __launch_bounds__(256) void loss_kernel(const float* __restrict__ mmd,
                                                   const int* __restrict__ qy,
                                                   float* __restrict__ out) {
  __shared__ float red[256];
  int tid = threadIdx.x;
  float val = 0.f;
  if (tid < 150) {
    float l[5];
    float mx = -1e30f;
#pragma unroll
    for (int w = 0; w < 5; w++) {
      l[w] = -mmd[tid * 5 + w] * (1.0f / 12.5f);
      mx = fmaxf(mx, l[w]);
    }
    float sum = 0.f;
#pragma unroll
    for (int w = 0; w < 5; w++) sum += __expf(l[w] - mx);
    float lse = mx + logf(sum);
    int y = qy[tid];
    val = -(l[y] - lse);
  }
  red[tid] = val;
  __syncthreads();
  for (int s = 128; s > 0; s >>= 1) {
    if (tid < s) red[tid] += red[tid + s];
    __syncthreads();
  }
  if (tid == 0) out[0] = red[0] * (1.0f / 150.0f);
}

// =====================================================================
extern "C" void kernel_launch(void* const* d_in, const int* in_sizes, int n_in,
                              void* d_out, int out_size, void* d_ws, size_t ws_size,
                              hipStream_t stream) {
  (void)in_sizes; (void)n_in; (void)out_size;
  const float* sup = (const float*)d_in[0];
  const float* qry = (const float*)d_in[2];
  const int* qy = (const int*)d_in[3];
  const float* Wq = (const float*)d_in[4];
  const float* Wk = (const float*)d_in[5];
  const float* Wv = (const float*)d_in[6];
  float* ws = (float*)d_ws;
  unsigned short* XTB = (unsigned short*)(ws + XTB_OFF);
  unsigned short* WB = (unsigned short*)(ws + WB_OFF);
  unsigned short* projB = (unsigned short*)(ws + PROJB_OFF);
  float* mmd = ws + MMD_OFF;
  unsigned short* feat = (unsigned short*)(ws + FEAT_OFF);
  float* out = (float*)d_out;

  long wsf = (long)(ws_size / 4);
  long avail_us = (wsf - FEAT_OFF) * 2;
  long chunkL = avail_us / FEAT_PER_PAIR_US;
  int chunk = (chunkL > 150) ? 150 : (chunkL < 1 ? 1 : (int)chunkL);

  hipLaunchKernelGGL(t_kernel, dim3(200), dim3(256), 0, stream, sup, qry, XTB);
  hipLaunchKernelGGL(w_kernel, dim3(600), dim3(256), 0, stream, Wq, Wk, Wv, WB);
  hipLaunchKernelGGL(proj_kernel, dim3(40, 5, 3), dim3(512), 0, stream, WB, XTB, projB);
  for (int c0 = 0; c0 < 150; c0 += chunk) {
    int cp = (150 - c0 < chunk) ? (150 - c0) : chunk;
    hipLaunchKernelGGL(attn_kernel, dim3(cp * 50), dim3(256), 0, stream, projB, XTB, feat, c0);
    hipLaunchKernelGGL(gram_kernel, dim3(cp * 5), dim3(512), 0, stream, feat, mmd, c0);
  }
  hipLaunchKernelGGL(loss_kernel, dim3(1), dim3(256), 0, stream, mmd, qy, out);
}